// Round 10
// baseline (938.466 us; speedup 1.0000x reference)
//
#include <hip/hip_runtime.h>
#include <cstdint>

// ============================================================================
// ParallelTransformerBlock (PaLM-style parallel attn+FF, MQA, RoPE, LoRA)
// B=2, N=2048, DIM=2048, HEADS=16, DIM_HEAD=64 (MQA), FF_INNER=8192, R=8.
//
// R13 (vs R12): attn's __launch_bounds__(256,4) REVERTED to (256,2).
//   R11 crashed the container twice; R12 failed post-timing replay checks
//   (absmax 2.18, intermittent). Only untested change was the forced
//   4-blocks/CU VGPR cap (<=128) -> spill-to-scratch in a gload_lds-dense
//   loop. The grid un-pairing itself is provably disjoint and kept:
//   grid (32,32)=1024 blocks, qt=31-blockIdx.x (longest first). If natural
//   VGPR <=128 the HW still co-schedules >2 blocks/CU (LDS 32KB allows 5).
//  - ff: ONE dispatch (R6 best-measured form, 259 us).
//  - gemm2: R10 verbatim (measured 173 us, MfmaUtil 39%).
// ============================================================================

typedef __bf16 bf16_t;
typedef __bf16 bf16x8 __attribute__((ext_vector_type(8)));
typedef float f32x4 __attribute__((ext_vector_type(4)));

#define LOG2E 1.44269504088896340736f
#define LOG2_10K 13.287712379549449f   // log2(10000)

// s_waitcnt simm16 (gfx9-class): vmcnt[3:0]=bits3:0, expcnt=bits6:4,
// lgkmcnt=bits11:8, vmcnt[5:4]=bits15:14.
#define WAITCNT_VM(N) __builtin_amdgcn_s_waitcnt(0x0F70 | (N))   // vmcnt(N) only

__device__ __forceinline__ void gload_lds16(const void* g, void* l) {
  __builtin_amdgcn_global_load_lds(
      (__attribute__((address_space(1))) void*)(uintptr_t)g,
      (__attribute__((address_space(3))) void*)(uint32_t)(uintptr_t)l,
      16, 0, 0);
}

__device__ __forceinline__ f32x4 mfma16(bf16x8 a, bf16x8 b, f32x4 c) {
  return __builtin_amdgcn_mfma_f32_16x16x32_bf16(a, b, c, 0, 0, 0);
}

// ---------------------------------------------------------------------------
// LayerNorm: one block per token row (4096 rows x 2048)
// ---------------------------------------------------------------------------
__global__ __launch_bounds__(256) void ln_kernel(
    const float* __restrict__ x, const float* __restrict__ gamma,
    bf16_t* __restrict__ xn)
{
  const int row = blockIdx.x;
  const int t = threadIdx.x;
  const float4* xr = (const float4*)(x + (size_t)row * 2048);
  float4 a = xr[t * 2];
  float4 b = xr[t * 2 + 1];
  float s  = a.x + a.y + a.z + a.w + b.x + b.y + b.z + b.w;
  float ss = a.x*a.x + a.y*a.y + a.z*a.z + a.w*a.w
           + b.x*b.x + b.y*b.y + b.z*b.z + b.w*b.w;
  #pragma unroll
  for (int m = 1; m < 64; m <<= 1) {
    s  += __shfl_xor(s, m);
    ss += __shfl_xor(ss, m);
  }
  __shared__ float red[8];
  const int wave = t >> 6, lane = t & 63;
  if (lane == 0) { red[wave] = s; red[4 + wave] = ss; }
  __syncthreads();
  const float stot  = red[0] + red[1] + red[2] + red[3];
  const float sstot = red[4] + red[5] + red[6] + red[7];
  const float mu  = stot * (1.f / 2048.f);
  const float var = sstot * (1.f / 2048.f) - mu * mu;
  const float rs  = rsqrtf(var + 1e-5f);
  float v[8] = {a.x, a.y, a.z, a.w, b.x, b.y, b.z, b.w};
  bf16x8 o;
  #pragma unroll
  for (int e = 0; e < 8; ++e)
    o[e] = (bf16_t)((v[e] - mu) * rs * gamma[t * 8 + e]);
  *(bf16x8*)(xn + (size_t)row * 2048 + t * 8) = o;
}

// ---------------------------------------------------------------------------
// Transpose+convert w_fused (2048 x 17536 f32) -> wfT (17536 x 2048 bf16),
// folding lora_q/k/v into cols [0,1152). 64x64 tiles, LDS pad +1.
// ---------------------------------------------------------------------------
__global__ __launch_bounds__(256) void transpose_wf_kernel(
    const float* __restrict__ w,
    const float* __restrict__ qa, const float* __restrict__ qb,
    const float* __restrict__ ka, const float* __restrict__ kb,
    const float* __restrict__ va, const float* __restrict__ vb,
    bf16_t* __restrict__ wfT)
{
  __shared__ float tile[64][65];
  const int t  = threadIdx.x;
  const int n0 = blockIdx.x * 64;
  const int k0 = blockIdx.y * 64;
  #pragma unroll
  for (int it = 0; it < 4; ++it) {
    const int kr = (t >> 4) + it * 16;
    const float4 vv = *(const float4*)(w + (size_t)(k0 + kr) * 17536 + n0 + (t & 15) * 4);
    tile[kr][(t & 15) * 4 + 0] = vv.x;
    tile[kr][(t & 15) * 4 + 1] = vv.y;
    tile[kr][(t & 15) * 4 + 2] = vv.z;
    tile[kr][(t & 15) * 4 + 3] = vv.w;
  }
  __syncthreads();
  const float* la = nullptr; const float* lb = nullptr;
  int nbo = 0, ldlb = 0;
  if (n0 < 1024)      { la = qa; lb = qb; nbo = n0;        ldlb = 1024; }
  else if (n0 < 1088) { la = ka; lb = kb; nbo = n0 - 1024; ldlb = 64;   }
  else if (n0 < 1152) { la = va; lb = vb; nbo = n0 - 1088; ldlb = 64;   }
  #pragma unroll
  for (int it = 0; it < 2; ++it) {
    const int nl = (t >> 3) + it * 32;
    const int kl = (t & 7) * 8;
    float vals[8];
    #pragma unroll
    for (int e = 0; e < 8; ++e) vals[e] = tile[kl + e][nl];
    if (la) {
      float bc[8];
      #pragma unroll
      for (int r = 0; r < 8; ++r) bc[r] = lb[r * ldlb + nbo + nl];
      #pragma unroll
      for (int e = 0; e < 8; ++e) {
        const float* ar = la + (size_t)(k0 + kl + e) * 8;
        float d = 0.f;
        #pragma unroll
        for (int r = 0; r < 8; ++r) d += ar[r] * bc[r];
        vals[e] += d;
      }
    }
    bf16x8 o;
    #pragma unroll
    for (int e = 0; e < 8; ++e) o[e] = (bf16_t)vals[e];
    *(bf16x8*)(wfT + (size_t)(n0 + nl) * 2048 + k0 + kl) = o;
  }
}

// ---------------------------------------------------------------------------
// Build w2T (2048 x 9216 bf16): cols [0,8192) = w_ff_out^T,
// cols [8192,9216) = (w_attn_out + lora_o_a@lora_o_b)^T.
// ---------------------------------------------------------------------------
__global__ __launch_bounds__(256) void transpose_w2_kernel(
    const float* __restrict__ wff,   // 8192 x 2048
    const float* __restrict__ watt,  // 1024 x 2048
    const float* __restrict__ oa, const float* __restrict__ ob,
    bf16_t* __restrict__ w2T)
{
  __shared__ float tile[64][65];
  const int t  = threadIdx.x;
  const int n0 = blockIdx.x * 64;
  const int k0 = blockIdx.y * 64;          // 0..9152
  const bool isatt = (k0 >= 8192);
  const float* src = isatt ? (watt + (size_t)(k0 - 8192) * 2048)
                           : (wff + (size_t)k0 * 2048);
  #pragma unroll
  for (int it = 0; it < 4; ++it) {
    const int kr = (t >> 4) + it * 16;
    const float4 vv = *(const float4*)(src + (size_t)kr * 2048 + n0 + (t & 15) * 4);
    tile[kr][(t & 15) * 4 + 0] = vv.x;
    tile[kr][(t & 15) * 4 + 1] = vv.y;
    tile[kr][(t & 15) * 4 + 2] = vv.z;
    tile[kr][(t & 15) * 4 + 3] = vv.w;
  }
  __syncthreads();
  #pragma unroll
  for (int it = 0; it < 2; ++it) {
    const int nl = (t >> 3) + it * 32;
    const int kl = (t & 7) * 8;
    float vals[8];
    #pragma unroll
    for (int e = 0; e < 8; ++e) vals[e] = tile[kl + e][nl];
    if (isatt) {
      float bc[8];
      #pragma unroll
      for (int r = 0; r < 8; ++r) bc[r] = ob[r * 2048 + n0 + nl];
      #pragma unroll
      for (int e = 0; e < 8; ++e) {
        const float* ar = oa + (size_t)(k0 - 8192 + kl + e) * 8;
        float d = 0.f;
        #pragma unroll
        for (int r = 0; r < 8; ++r) d += ar[r] * bc[r];
        vals[e] += d;
      }
    }
    bf16x8 o;
    #pragma unroll
    for (int e = 0; e < 8; ++e) o[e] = (bf16_t)vals[e];
    *(bf16x8*)(w2T + (size_t)(n0 + nl) * 9216 + k0 + kl) = o;
  }
}

// ---------------------------------------------------------------------------
// Single-B GEMM core: C[128x128] += A * BT^T (16 MFMA/barrier).  (qkv only)
// ---------------------------------------------------------------------------
__device__ __forceinline__ void gemm_core_128x128(
    const bf16_t* __restrict__ A, int ldA, int m0,
    const bf16_t* __restrict__ BT, int ldB, int n0,
    int K, bf16_t* As, bf16_t* Bs, f32x4* acc)
{
  const int t = threadIdx.x;
  const int wave = t >> 6;
  const int lane = t & 63;
  const int quad = lane >> 4;
  const int ln15 = lane & 15;
  const int wm = wave & 1, wn = wave >> 1;

  const bf16_t* gA = A + (size_t)(m0 + (t >> 2)) * ldA + ((t & 3) << 3);
  const bf16_t* gB = BT + (size_t)(n0 + (t >> 2)) * ldB + ((t & 3) << 3);
  char* lA = (char*)As + wave * 1024;
  char* lB = (char*)Bs + wave * 1024;
  const size_t sA64 = (size_t)64 * ldA;
  const size_t sB64 = (size_t)64 * ldB;
  const int aoff = (wm * 64 + ln15) * 32 + quad * 8;
  const int boff = (wn * 64 + ln15) * 32 + quad * 8;

  for (int kt = 0; kt < K; kt += 32) {
    gload_lds16(gA,        lA);
    gload_lds16(gA + sA64, lA + 4096);
    gload_lds16(gB,        lB);
    gload_lds16(gB + sB64, lB + 4096);
    gA += 32;
    gB += 32;
    __syncthreads();
    bf16x8 a0 = *(const bf16x8*)(As + aoff);
    bf16x8 a1 = *(const bf16x8*)(As + aoff + 512);
    bf16x8 a2 = *(const bf16x8*)(As + aoff + 1024);
    bf16x8 a3 = *(const bf16x8*)(As + aoff + 1536);
    bf16x8 b0 = *(const bf16x8*)(Bs + boff);
    bf16x8 b1 = *(const bf16x8*)(Bs + boff + 512);
    bf16x8 b2 = *(const bf16x8*)(Bs + boff + 1024);
    bf16x8 b3 = *(const bf16x8*)(Bs + boff + 1536);
    acc[0]  = mfma16(a0, b0, acc[0]);
    acc[1]  = mfma16(a0, b1, acc[1]);
    acc[2]  = mfma16(a0, b2, acc[2]);
    acc[3]  = mfma16(a0, b3, acc[3]);
    acc[4]  = mfma16(a1, b0, acc[4]);
    acc[5]  = mfma16(a1, b1, acc[5]);
    acc[6]  = mfma16(a1, b2, acc[6]);
    acc[7]  = mfma16(a1, b3, acc[7]);
    acc[8]  = mfma16(a2, b0, acc[8]);
    acc[9]  = mfma16(a2, b1, acc[9]);
    acc[10] = mfma16(a2, b2, acc[10]);
    acc[11] = mfma16(a2, b3, acc[11]);
    acc[12] = mfma16(a3, b0, acc[12]);
    acc[13] = mfma16(a3, b1, acc[13]);
    acc[14] = mfma16(a3, b2, acc[14]);
    acc[15] = mfma16(a3, b3, acc[15]);
    __syncthreads();
  }
}

// ---------------------------------------------------------------------------
// Dual-B GEMM core: one A tile, two B tiles, 32 MFMA/barrier.  (qkv only)
// ---------------------------------------------------------------------------
__device__ __forceinline__ void gemm_core_dual(
    const bf16_t* gA, const bf16_t* gB0, const bf16_t* gB1,
    int ldA, int ldB, int K,
    bf16_t* As, bf16_t* B0s, bf16_t* B1s,
    f32x4* acc0, f32x4* acc1)
{
  const int t = threadIdx.x;
  const int wave = t >> 6;
  const int lane = t & 63;
  const int quad = lane >> 4;
  const int ln15 = lane & 15;
  const int wm = wave & 1, wn = wave >> 1;

  char* lA = (char*)As + wave * 1024;
  char* l0 = (char*)B0s + wave * 1024;
  char* l1 = (char*)B1s + wave * 1024;
  const size_t sA64 = (size_t)64 * ldA;
  const size_t sB64 = (size_t)64 * ldB;
  const int aoff = (wm * 64 + ln15) * 32 + quad * 8;
  const int boff = (wn * 64 + ln15) * 32 + quad * 8;

  for (int kt = 0; kt < K; kt += 32) {
    gload_lds16(gA,         lA);
    gload_lds16(gA + sA64,  lA + 4096);
    gload_lds16(gB0,        l0);
    gload_lds16(gB0 + sB64, l0 + 4096);
    gload_lds16(gB1,        l1);
    gload_lds16(gB1 + sB64, l1 + 4096);
    gA += 32; gB0 += 32; gB1 += 32;
    __syncthreads();
    bf16x8 a0 = *(const bf16x8*)(As + aoff);
    bf16x8 a1 = *(const bf16x8*)(As + aoff + 512);
    bf16x8 a2 = *(const bf16x8*)(As + aoff + 1024);
    bf16x8 a3 = *(const bf16x8*)(As + aoff + 1536);
    bf16x8 p0 = *(const bf16x8*)(B0s + boff);
    bf16x8 p1 = *(const bf16x8*)(B0s + boff + 512);
    bf16x8 p2 = *(const bf16x8*)(B0s + boff + 1024);
    bf16x8 p3 = *(const bf16x8*)(B0s + boff + 1536);
    bf16x8 q0 = *(const bf16x8*)(B1s + boff);
    bf16x8 q1 = *(const bf16x8*)(B1s + boff + 512);
    bf16x8 q2 = *(const bf16x8*)(B1s + boff + 1024);
    bf16x8 q3 = *(const bf16x8*)(B1s + boff + 1536);
    acc0[0]  = mfma16(a0, p0, acc0[0]);
    acc0[1]  = mfma16(a0, p1, acc0[1]);
    acc0[2]  = mfma16(a0, p2, acc0[2]);
    acc0[3]  = mfma16(a0, p3, acc0[3]);
    acc1[0]  = mfma16(a0, q0, acc1[0]);
    acc1[1]  = mfma16(a0, q1, acc1[1]);
    acc1[2]  = mfma16(a0, q2, acc1[2]);
    acc1[3]  = mfma16(a0, q3, acc1[3]);
    acc0[4]  = mfma16(a1, p0, acc0[4]);
    acc0[5]  = mfma16(a1, p1, acc0[5]);
    acc0[6]  = mfma16(a1, p2, acc0[6]);
    acc0[7]  = mfma16(a1, p3, acc0[7]);
    acc1[4]  = mfma16(a1, q0, acc1[4]);
    acc1[5]  = mfma16(a1, q1, acc1[5]);
    acc1[6]  = mfma16(a1, q2, acc1[6]);
    acc1[7]  = mfma16(a1, q3, acc1[7]);
    acc0[8]  = mfma16(a2, p0, acc0[8]);
    acc0[9]  = mfma16(a2, p1, acc0[9]);
    acc0[10] = mfma16(a2, p2, acc0[10]);
    acc0[11] = mfma16(a2, p3, acc0[11]);
    acc1[8]  = mfma16(a2, q0, acc1[8]);
    acc1[9]  = mfma16(a2, q1, acc1[9]);
    acc1[10] = mfma16(a2, q2, acc1[10]);
    acc1[11] = mfma16(a2, q3, acc1[11]);
    acc0[12] = mfma16(a3, p0, acc0[12]);
    acc0[13] = mfma16(a3, p1, acc0[13]);
    acc0[14] = mfma16(a3, p2, acc0[14]);
    acc0[15] = mfma16(a3, p3, acc0[15]);
    acc1[12] = mfma16(a3, q0, acc1[12]);
    acc1[13] = mfma16(a3, q1, acc1[13]);
    acc1[14] = mfma16(a3, q2, acc1[14]);
    acc1[15] = mfma16(a3, q3, acc1[15]);
    __syncthreads();
  }
}

// ---------------------------------------------------------------------------
// GEMM1a (qkv cols 0..1151), RoPE + layout fused. (exact R6)
// ---------------------------------------------------------------------------
__global__ __launch_bounds__(256, 2) void gemm1_qkv_kernel(
    const bf16_t* __restrict__ xn, const bf16_t* __restrict__ wfT,
    bf16_t* __restrict__ Q, bf16_t* __restrict__ K, bf16_t* __restrict__ Vt)
{
  __shared__ __align__(16) bf16_t As[128 * 32];
  __shared__ __align__(16) bf16_t B0s[128 * 32];
  __shared__ __align__(16) bf16_t B1s[128 * 32];
  const int m0 = blockIdx.x * 128;
  const int y = blockIdx.y;
  const int t = threadIdx.x;
  const int wave = t >> 6, lane = t & 63;
  const int quad = lane >> 4, ln15 = lane & 15;
  const int wm = wave & 1, wn = wave >> 1;

  const int rb = m0 + wm * 64 + quad * 4;
  const float invf0 = exp2f(-(float)ln15 * (LOG2_10K / 32.0f));
  const float invf1 = exp2f(-(float)(16 + ln15) * (LOG2_10K / 32.0f));

  if (y < 4) {
    const bf16_t* gA  = xn  + (size_t)(m0 + (t >> 2)) * 2048 + ((t & 3) << 3);
    const bf16_t* gB0 = wfT + (size_t)(y * 256 + (t >> 2)) * 2048 + ((t & 3) << 3);
    const bf16_t* gB1 = wfT + (size_t)(y * 256 + 128 + (t >> 2)) * 2048 + ((t & 3) << 3);
    f32x4 acc0[16], acc1[16];
    #pragma unroll
    for (int f = 0; f < 16; ++f) {
      acc0[f] = (f32x4){0.f, 0.f, 0.f, 0.f};
      acc1[f] = (f32x4){0.f, 0.f, 0.f, 0.f};
    }
    gemm_core_dual(gA, gB0, gB1, 2048, 2048, 2048, As, B0s, B1s, acc0, acc1);
    #pragma unroll
    for (int half = 0; half < 2; ++half) {
      const f32x4* acc = half ? acc1 : acc0;
      const int hd = y * 4 + half * 2 + wn;
      #pragma unroll
      for (int i = 0; i < 4; ++i) {
        #pragma unroll
        for (int rr = 0; rr < 4; ++rr) {
          const int row = rb + i * 16 + rr;
          const int b = row >> 11, n = row & 2047;
          const float fn = (float)n;
          float s0, c0, s1, c1;
          __sincosf(fn * invf0, &s0, &c0);
          __sincosf(fn * invf1, &s1, &c1);
          float vals[4];
          #pragma unroll
          for (int j = 0; j < 4; ++j) vals[j] = acc[i * 4 + j][rr];
          #pragma unroll
          for (int j = 0; j < 4; ++j) {
            const float rot = (j < 2) ? -vals[j + 2] : vals[j - 2];
            const float c = (j & 1) ? c1 : c0;
            const float s = (j & 1) ? s1 : s0;
            const float o = (vals[j] * c + rot * s) * 0.125f;
            Q[(((size_t)b * 16 + hd) * 2048 + n) * 64 + j * 16 + ln15] = (bf16_t)o;
          }
        }
      }
    }
  } else {
    f32x4 acc[16];
    #pragma unroll
    for (int f = 0; f < 16; ++f) acc[f] = (f32x4){0.f, 0.f, 0.f, 0.f};
    gemm_core_128x128(xn, 2048, m0, wfT, 2048, 1024, 2048, As, B0s, acc);
    const bool is_k = (wn == 0);
    #pragma unroll
    for (int i = 0; i < 4; ++i) {
      #pragma unroll
      for (int rr = 0; rr < 4; ++rr) {
        const int row = rb + i * 16 + rr;
        const int b = row >> 11, n = row & 2047;
        float vals[4];
        #pragma unroll
        for (int j = 0; j < 4; ++j) vals[j] = acc[i * 4 + j][rr];
        if (is_k) {
          const float fn = (float)n;
          float s0, c0, s1, c1;
          __sincosf(fn * invf0, &s0, &c0);
          __sincosf(fn * invf1, &s1, &c1);
          #pragma unroll
          for (int j = 0; j < 4; ++j) {
            const float rot = (j < 2) ? -vals[j + 2] : vals[j - 2];
            const float c = (j & 1) ? c1 : c0;
            const float s = (j & 1) ? s1 : s0;
            K[((size_t)b * 2048 + n) * 64 + j * 16 + ln15] = (bf16_t)(vals[j] * c + rot * s);
          }
        } else {
          #pragma unroll
          for (int j = 0; j < 4; ++j)
            Vt[((size_t)b * 64 + j * 16 + ln15) * 2048 + n] = (bf16_t)vals[j];
        }
      }
    }
  }
}

// ===========================================================================
// ff: exact R6 core (reg-prefetch pipeline), single dispatch.
// ===========================================================================

#define FF_STG() {                                                           \
    char* lA_ = lds + sst + w * 1024;                                        \
    gload_lds16(gA, lA_);                                                    \
    gload_lds16(gA + (size_t)128 * 2048, lA_ + 8192);                        \
    char* lB_ = lds + 65536 + sst + w * 1024;                                \
    gload_lds16(gB0, lB_);                                                   \
    gload_lds16(gB1, lB_ + 8192);                                            \
    gA += 32; gB0 += 32; gB1 += 32;                                          \
    sst = (sst + 16384) & 65535; }

#define FF_RD(DA, DB) {                                                      \
    _Pragma("unroll")                                                        \
    for (int mf_ = 0; mf_ < 8; ++mf_)                                        \
      DA[mf_] = *(const bf16x8*)(lds + srd + wm * 8192 + mf_ * 1024 + ro);   \
    _Pragma("unroll")                                                        \
    for (int nf_ = 0; nf_ < 4; ++nf_)                                        \
      DB[nf_] = *(const bf16x8*)(lds + 65536 + srd + wn * 4096 + nf_ * 1024 + ro); \
    srd = (srd + 16384) & 65535;                                             \
    __builtin_amdgcn_sched_barrier(0); }

#define FF_MM(SA, SB) {                                                      \
    __builtin_amdgcn_s_setprio(1);                                           \
    _Pragma("unroll")                                                        \
    for (int mf_ = 0; mf_ < 8; ++mf_) {                                      \
      _Pragma("unroll")                                                      \
      for (int nf_ = 0; nf_ < 4; ++nf_)                                      \
        acc[mf_][nf_] = mfma16(SA[mf_], SB[nf_], acc[mf_][nf_]);             \
    }                                                                        \
    __builtin_amdgcn_s_setprio(0); }

#define FF_SYNC4() { WAITCNT_VM(4); __builtin_amdgcn_s_barrier(); }

// ---------------------------------------------------------------------------
// GEMM1b (ff): BM=256, B = 128 gate + 128 x rows interleaved (16-row), BK=32,
// 512 thr (8 waves 2Mx4N). 4-slot LDS ring (128 KB), reg-prefetch pipeline.
// ---------------------------------------------------------------------------
__global__ __launch_bounds__(512, 2) void gemm1_ff_kernel(
    const bf16_t* __restrict__ xn, const bf16_t* __restrict__ wfT,
    bf16_t* __restrict__ A2)
{
  __shared__ __align__(16) char lds[131072];
  const int m0 = blockIdx.x * 256;
  const int c0 = blockIdx.y * 128;
  const int t = threadIdx.x;
  const int w = t >> 6, lane = t & 63;
  const int quad = lane >> 4, ln15 = lane & 15;
  const int wm = w & 1, wn = w >> 1;          // 2 x 4 wave grid

  const int p  = w * 64 + lane;
  const int r  = p >> 2;
  const int cl = (p & 3) ^ ((r >> 1) & 3);
  const bf16_t* gA = xn + (size_t)(m0 + r) * 2048 + cl * 8;
  const int r2 = r + 128;
  const int cm0 = c0 + ((r  >> 5) << 4) + (r  & 15);
  const int cm1 = c0 + ((r2 >> 5) << 4) + (r2 & 15);
  const int wr0 = ((r  >> 4) & 1) ? (1152 + cm0) : (9344 + cm0);
  const int wr1 = ((r2 >> 4) & 1) ? (1152 + cm1) : (9344 + cm1);
  const bf16_t* gB0 = wfT + (size_t)wr0 * 2048 + cl * 8;
  const bf16_t* gB1 = wfT + (size_t)wr1 * 2048 + cl * 8;

  const int ro = ln15 * 64 + ((quad ^ ((ln15 >> 1) & 3)) * 16);

  f32x4 acc[8][4];
  #pragma unroll
  for (int mf = 0; mf < 8; ++mf)
    #pragma unroll
    for (int nf = 0; nf < 4; ++nf)
      acc[mf][nf] = (f32x4){0.f, 0.f, 0.f, 0.f};

  int sst = 0, srd = 0;
  #pragma unroll
  for (int pt = 0; pt < 3; ++pt) FF_STG();
  FF_SYNC4();

  bf16x8 fA[8], fB[4], nA[8], nB[4];
  FF_RD(fA, fB);

  for (int i = 0; i < 30; ++i) {
    FF_STG(); FF_RD(nA, nB); FF_MM(fA, fB); FF_SYNC4();
    FF_STG(); FF_RD(fA, fB); FF_MM(nA, nB); FF_SYNC4();
  }
  FF_STG(); FF_RD(nA, nB); FF_MM(fA, fB); FF_SYNC4();
  FF_RD(fA, fB); FF_MM(nA, nB);
  WAITCNT_VM(0);
  __builtin_amdgcn_s_barrier();
  FF_RD(nA, nB); FF_MM(fA, fB);
  FF_MM(nA, nB);

  // epilogue: silu(gate)*x -> A2 cols [0,8192)
  const int row0 = m0 + wm * 128 + quad * 4;
  const int col0 = c0 + wn * 32 + ln15;
  #pragma unroll
  for (int mf = 0; mf < 8; ++mf)
    #pragma unroll
    for (int rr = 0; rr < 4; ++rr) {
      bf16_t* dst = A2 + (size_t)(row0 + mf * 16 + rr) * 9216 + col0;
      #pragma unroll
      for (int j = 0; j < 2; ++j) {
        const float g  = acc[mf][2 * j][rr];
        const float xv = acc[mf][2 * j + 1][rr];
        dst[j * 16] = (bf16_t)(xv * (g / (1.f + exp2f(-g * LOG2E))));
      }
    }
}

// ===========================================================================
// gemm2 (R10): ff-R6 clone. BM=256, BN=256 (dual 128-row w2T panels), BK=32,
// 512 thr (2Mx4N), 4-slot ring (128 KB), reg-prefetch, vm(4).
// Split-K=2: grid (16,8,2) = 256 blocks @ 1/CU. Atomic f32 epilogue.
// ===========================================================================

#define G2_STG() {                                                           \
    char* lA_ = lds + sst + w * 1024;                                        \
    gload_lds16(gA, lA_);                                                    \
    gload_lds16(gA + (size_t)128 * 9216, lA_ + 8192);                        \
    char* lB_ = lds + 65536 + sst + w * 1024;                                \
    gload_lds16(gB0, lB_);                                                   \
    gload_lds16(gB1, lB_ + 8192);                                            \
    gA += 32; gB0 += 32; gB1 += 32;                                          \
    sst = (sst + 16384) & 65535; }

__global__ __launch_bounds__(512, 2) void gemm2_kernel(
    const bf16_t* __restrict__ A2, const bf16_t* __restrict__ w2T,
    float* __restrict__ out)
{
  __shared__ __align__(16) char lds[131072];
  const int m0 = blockIdx.x * 256;
  const int n0 = blockIdx.y * 256;
  const int k0 = blockIdx.z * 4608;
  const int t = threadIdx.x;
  const int w = t >> 6, lane = t & 63;
  const int quad = lane >> 4, ln15 = lane & 15;
  const int wm = w & 1, wn = w >> 1;          // 2 x 4 wave grid

  const int p  = w * 64 + lane;
  const int r  = p >> 2;
  const int cl = (p & 3) ^ ((r >> 1) & 3);
  const bf16_t* gA  = A2  + (size_t)(m0 + r) * 9216 + k0 + cl * 8;
  const bf16_t* gB0 = w2T + (size_t)(n0 + r) * 9216 + k0 + cl * 8;
  const bf16_t* gB1 = w2T + (size_t)(n0 + 128 + r) * 9216 + k0 + cl * 8;

  const int ro = ln15 * 64 + ((quad ^ ((ln15 >> 1) & 3)) * 16);

  f32x4 acc[8][4];
  #pragma unroll
  for (int mf = 0; mf < 8; ++mf)
    #pragma unroll
    for (int nf = 0; nf < 4; ++nf)
      acc[mf][nf] = (f32x4){0.f, 0.f, 0.f, 0.f};

  int sst = 0, srd = 0;
  #pragma unroll
  for (int pt = 0; pt < 3; ++pt) G2_STG();
  FF_SYNC4();                      // tiles 0,1 done; tile 2 in flight

  bf16x8 fA[8], fB[4], nA[8], nB[4];
  FF_RD(fA, fB);                   // frags(0)

  // main: 144 K-steps per half (K=4608). tt = 0..140 uniform, tails 141..143.
  for (int i = 0; i < 70; ++i) {
    G2_STG(); FF_RD(nA, nB); FF_MM(fA, fB); FF_SYNC4();   // tt even
    G2_STG(); FF_RD(fA, fB); FF_MM(nA, nB); FF_SYNC4();   // tt odd
  }
  G2_STG(); FF_RD(nA, nB); FF_MM(fA, fB); FF_SYNC4();     // tt=140 (stages 143)
  FF_RD(fA, fB); FF_MM(nA, nB);                           // tt=141, reads 142
  WAITCNT_VM(0);
  __builtin_amdgcn_s_barrier();
  FF_RD(nA, nB); FF_MM(fA, fB);                           // tt=142, reads 143
  FF_MM(nA, nB);                                          // tt=143

  // epilogue: atomic accumulate (split-K)
  const int row0 = m0 + wm * 128 + quad * 4;
  const int col0 = n0 + wn * 64 + ln15;
  #pragma unroll
  for (int mf = 0; mf < 8; ++mf)
    #pragma unroll
    for (int rr = 0; rr < 4; ++rr) {
      float* dst = out + (size_t)(row0 + mf * 16 + rr) * 2048 + col0;
      #pragma unroll
      for (int nf = 0; nf < 4; ++nf)
        unsafeAtomicAdd(dst + nf * 16, acc[mf][nf][rr]);
    }
}

// ---------------------------------------------------------------------------
// Causal MQA flash attention -> A2[:, 8192 + h*64 + d].
// Un-paired Q-tiles: grid (32,32)=1024 blocks, qt=31-blockIdx.x (longest
// first). launch_bounds(256,2) — natural VGPR budget; HW co-schedules more
// blocks/CU if registers allow (LDS 32KB permits 5). Inner loop = R6.
// ---------------------------------------------------------------------------
__global__ __launch_bounds__(256, 2) void attn_kernel(
    const bf16_t* __restrict__ Q, const bf16_t* __restrict__ Kg_,
    const bf16_t* __restrict__ Vt, bf16_t* __restrict__ A2)
{
  __shared__ __align__(16) bf16_t Qs[64 * 64];
  __shared__ __align__(16) bf16_t Ks[64 * 64];
  __shared__ __align__(16) bf16_t Vs[64 * 64];
  __shared__ __align__(16) bf16_t Ps[64 * 64];
  const int bh = blockIdx.y;
  const int b = bh >> 4, h = bh & 15;
  const int t = threadIdx.x;
  const int wave = t >> 6, lane = t & 63;
  const int quad = lane >> 4, ln15 = lane & 15;

  const bf16_t* Kg = Kg_ + (size_t)b * 2048 * 64;
  const bf16_t* Vg = Vt + (size_t)b * 64 * 2048;

  const int qt = 31 - blockIdx.x;        // longest (qt=31) first
  const int qm0 = qt * 64;
  const bf16_t* Qg = Q + ((size_t)bh * 2048 + qm0) * 64;

  { // stage Q tile (8 KB, 2 rounds)
    const bf16_t* g = Qg + (size_t)(t >> 3) * 64 + ((t & 7) << 3);
    char* l = (char*)Qs + wave * 1024;
    gload_lds16(g,           l);
    gload_lds16(g + 32 * 64, l + 4096);
  }

  float mstate[4], lstate[4];
  f32x4 o_acc[4];
  #pragma unroll
  for (int rr = 0; rr < 4; ++rr) { mstate[rr] = -1e30f; lstate[rr] = 0.f; }
  #pragma unroll
  for (int jd = 0; jd < 4; ++jd) o_acc[jd] = (f32x4){0.f, 0.f, 0.f, 0.f};

  const int njt = qt + 1;
  for (int jt = 0; jt < njt; ++jt) {
    { // stage K, V tiles (8 KB each)
      const bf16_t* kg = Kg + (size_t)(jt * 64 + (t >> 3)) * 64 + ((t & 7) << 3);
      char* lk = (char*)Ks + wave * 1024;
      gload_lds16(kg,           lk);
      gload_lds16(kg + 32 * 64, lk + 4096);
      const bf16_t* vg = Vg + (size_t)(t >> 3) * 2048 + jt * 64 + ((t & 7) << 3);
      char* lv = (char*)Vs + wave * 1024;
      gload_lds16(vg,                   lv);
      gload_lds16(vg + (size_t)32*2048, lv + 4096);
    }
    __syncthreads();

    f32x4 sA[4];
    #pragma unroll
    for (int j = 0; j < 4; ++j) sA[j] = (f32x4){0.f, 0.f, 0.f, 0.f};
    #pragma unroll
    for (int ks = 0; ks < 2; ++ks) {
      bf16x8 aq = *(const bf16x8*)(Qs + (wave * 16 + ln15) * 64 + ks * 32 + quad * 8);
      #pragma unroll
      for (int j = 0; j < 4; ++j) {
        bf16x8 bk = *(const bf16x8*)(Ks + (j * 16 + ln15) * 64 + ks * 32 + quad * 8);
        sA[j] = mfma16(aq, bk, sA[j]);
      }
    }

    const bool needmask = (jt * 64 + 63 > qm0 + wave * 16);
    const int row0 = qm0 + wave * 16 + quad * 4;
    float alpha[4];
    #pragma unroll
    for (int rr = 0; rr < 4; ++rr) {
      const int rowg = row0 + rr;
      if (needmask) {
        #pragma unroll
        for (int j = 0; j < 4; ++j) {
          const int colg = jt * 64 + j * 16 + ln15;
          if (colg > rowg) sA[j][rr] = -1e30f;
        }
      }
      float mx = fmaxf(fmaxf(sA[0][rr], sA[1][rr]),
                       fmaxf(sA[2][rr], sA[3][rr]));
      mx = fmaxf(mx, __shfl_xor(mx, 1));
      mx = fmaxf(mx, __shfl_xor(mx, 2));
      mx = fmaxf(mx, __shfl_xor(mx, 4));
      mx = fmaxf(mx, __shfl_xor(mx, 8));
      const float mold = mstate[rr];
      const float mnew = fmaxf(mold, mx);
      const float al = exp2f((mold - mnew) * LOG2E);
      float rsum = 0.f;
      #pragma unroll
      for (int j = 0; j < 4; ++j) {
        const float p = exp2f((sA[j][rr] - mnew) * LOG2E);
        sA[j][rr] = p;
        rsum += p;
      }
      rsum += __shfl_xor(rsum, 1);
      rsum += __shfl_xor(rsum, 2);
      rsum += __shfl_xor(rsum, 4);
      rsum += __shfl_xor(rsum, 8);
      lstate[rr] = lstate[rr] * al + rsum;
      mstate[rr] = mnew;
      alpha[rr] = al;
    }
    #pragma unroll
    for (int jd = 0; jd < 4; ++jd)
      #pragma unroll
      for (int rr = 0; rr < 4; ++rr)
        o_acc[jd][rr] *= alpha[rr];
    #pragma unroll
    for (int j = 0; j < 4; ++j)
      #pragma unroll
      for (int rr = 0; rr < 4; ++rr)
        Ps[wave * 1024 + (quad * 4 + rr) * 64 + j * 16 + ln15] = (bf16_t)sA[j][rr];

    #pragma unroll
    for (int ks = 0; ks < 2; ++ks) {
      bf16x8 ap = *(const bf16x8*)(Ps + wave * 1024 + ln15 * 64 + ks * 32 + quad * 8);
      #pragma unroll
      for (int jd = 0; jd < 4; ++jd) {
        bf16x8 bv = *(const bf16x8*)(Vs + (jd * 16 + ln15) * 64 + ks * 32 + quad * 8);
        o_acc[jd] = mfma16(ap, bv, o_acc[jd]);
      }
    }
    __syncthreads();
  }

  const int row0 = qm0 + wave * 16 + quad * 4;
  #pragma unroll
  for (int rr = 0; rr < 4; ++rr) {
    const float inv = 1.f / lstate[rr];
    bf16_t* dst = A2 + ((size_t)b * 2048 + row0 + rr) * 9216 + 8192 + h * 64 + ln15;
    #pragma unroll
    for (int jd = 0; jd < 4; ++jd)
      dst[jd * 16] = (bf16_t)(o_acc[jd][rr] * inv);
  }
}

// ---------------------------------------------------------------------------
extern "C" void kernel_launch(void* const* d_in, const int* in_sizes, int n_in,
                              void* d_out, int out_size, void* d_ws, size_t ws_size,
                              hipStream_t stream)
{
  const float* x      = (const float*)d_in[0];
  const float* gamma  = (const float*)d_in[1];
  const float* wfused = (const float*)d_in[2];
  const float* watt   = (const float*)d_in[3];
  const float* wff    = (const float*)d_in[4];
  const float* qa     = (const float*)d_in[5];
  const float* qb     = (const float*)d_in[6];
  const float* ka     = (const float*)d_in[7];
  const float* kb     = (const float*)d_in[8];
  const float* va     = (const float*)d_in[9];
  const float* vb     = (const float*)d_in[10];
  const float* oa     = (const float*)d_in[11];
  const float* ob     = (const float*)d_in[12];
  float* out = (float*)d_out;

  char* ws = (char*)d_ws;
  bf16_t* xn  = (bf16_t*)(ws);                    // 16,777,216
  bf16_t* wfT = (bf16_t*)(ws + 16777216);         // 71,827,456
  bf16_t* w2T = (bf16_t*)(ws + 88604672);         // 37,748,736
  bf16_t* A2  = (bf16_t*)(ws + 126353408);        // 75,497,472
  bf16_t* Qr  = (bf16_t*)(ws + 201850880);        //  8,388,608
  bf16_t* Kr  = (bf16_t*)(ws + 210239488);        //    524,288
  bf16_t* Vtr = (bf16_t*)(ws + 210763776);        //    524,288

  hipMemsetAsync(d_out, 0, (size_t)out_size * sizeof(float), stream);

  ln_kernel<<<dim3(4096), dim3(256), 0, stream>>>(x, gamma, xn);
  transpose_wf_kernel<<<dim3(274, 32), dim3(256), 0, stream>>>(
      wfused, qa, qb, ka, kb, va, vb, wfT);
  transpose_w2_kernel<<<dim3(32, 144), dim3(256), 0, stream>>>(
      wff, watt, oa, ob, w2T);
  gemm1_qkv_kernel<<<dim3(32, 5), dim3(256), 0, stream>>>(xn, wfT, Qr, Kr, Vtr);
  gemm1_ff_kernel<<<dim3(16, 64), dim3(512), 0, stream>>>(xn, wfT, A2);
  attn_kernel<<<dim3(32, 32), dim3(256), 0, stream>>>(Qr, Kr, Vtr, A2);
  gemm2_kernel<<<dim3(16, 8, 2), dim3(512), 0, stream>>>(A2, w2T, out);
}

// Round 11
// 878.171 us; speedup vs baseline: 1.0687x; 1.0687x over previous
//
#include <hip/hip_runtime.h>
#include <cstdint>

// ============================================================================
// ParallelTransformerBlock (PaLM-style parallel attn+FF, MQA, RoPE, LoRA)
// B=2, N=2048, DIM=2048, HEADS=16, DIM_HEAD=64 (MQA), FF_INNER=8192, R=8.
//
// R14: full revert to the exact R6 composition — the session's best-measured
// configuration (876.0/876.8/876.9 us across three runs):
//  - ff: single dispatch, 4-slot ring reg-prefetch, intrinsic waitcnt.
//  - gemm2: BM=256/BN=128, 512 thr, 4-slot ring reg-prefetch, grid 16x16,
//    direct f32 stores, NO split-K / memset / atomics.
//  - attn: paired Q-tiles (qt, 31-qt), grid (16,32), launch_bounds(256,2).
//  - qkv: syncthreads cores, grid (32,5).
// Deviations tried and measured worse: gemm2 128^2 re-tile (+20/+42), attn+qkv
// double-buffer (+25), gemm2 ff-clone+atomics (+29 net), attn un-pairing
// (+32 at natural occupancy; miscompiles at forced (256,4)).
// ============================================================================

typedef __bf16 bf16_t;
typedef __bf16 bf16x8 __attribute__((ext_vector_type(8)));
typedef float f32x4 __attribute__((ext_vector_type(4)));

#define LOG2E 1.44269504088896340736f
#define LOG2_10K 13.287712379549449f   // log2(10000)

// s_waitcnt simm16 (gfx9-class): vmcnt[3:0]=bits3:0, expcnt=bits6:4,
// lgkmcnt=bits11:8, vmcnt[5:4]=bits15:14.
#define WAITCNT_VM(N) __builtin_amdgcn_s_waitcnt(0x0F70 | (N))   // vmcnt(N) only

__device__ __forceinline__ void gload_lds16(const void* g, void* l) {
  __builtin_amdgcn_global_load_lds(
      (__attribute__((address_space(1))) void*)(uintptr_t)g,
      (__attribute__((address_space(3))) void*)(uint32_t)(uintptr_t)l,
      16, 0, 0);
}

__device__ __forceinline__ f32x4 mfma16(bf16x8 a, bf16x8 b, f32x4 c) {
  return __builtin_amdgcn_mfma_f32_16x16x32_bf16(a, b, c, 0, 0, 0);
}

// ---------------------------------------------------------------------------
// LayerNorm: one block per token row (4096 rows x 2048)
// ---------------------------------------------------------------------------
__global__ __launch_bounds__(256) void ln_kernel(
    const float* __restrict__ x, const float* __restrict__ gamma,
    bf16_t* __restrict__ xn)
{
  const int row = blockIdx.x;
  const int t = threadIdx.x;
  const float4* xr = (const float4*)(x + (size_t)row * 2048);
  float4 a = xr[t * 2];
  float4 b = xr[t * 2 + 1];
  float s  = a.x + a.y + a.z + a.w + b.x + b.y + b.z + b.w;
  float ss = a.x*a.x + a.y*a.y + a.z*a.z + a.w*a.w
           + b.x*b.x + b.y*b.y + b.z*b.z + b.w*b.w;
  #pragma unroll
  for (int m = 1; m < 64; m <<= 1) {
    s  += __shfl_xor(s, m);
    ss += __shfl_xor(ss, m);
  }
  __shared__ float red[8];
  const int wave = t >> 6, lane = t & 63;
  if (lane == 0) { red[wave] = s; red[4 + wave] = ss; }
  __syncthreads();
  const float stot  = red[0] + red[1] + red[2] + red[3];
  const float sstot = red[4] + red[5] + red[6] + red[7];
  const float mu  = stot * (1.f / 2048.f);
  const float var = sstot * (1.f / 2048.f) - mu * mu;
  const float rs  = rsqrtf(var + 1e-5f);
  float v[8] = {a.x, a.y, a.z, a.w, b.x, b.y, b.z, b.w};
  bf16x8 o;
  #pragma unroll
  for (int e = 0; e < 8; ++e)
    o[e] = (bf16_t)((v[e] - mu) * rs * gamma[t * 8 + e]);
  *(bf16x8*)(xn + (size_t)row * 2048 + t * 8) = o;
}

// ---------------------------------------------------------------------------
// Transpose+convert w_fused (2048 x 17536 f32) -> wfT (17536 x 2048 bf16),
// folding lora_q/k/v into cols [0,1152). 64x64 tiles, LDS pad +1.
// ---------------------------------------------------------------------------
__global__ __launch_bounds__(256) void transpose_wf_kernel(
    const float* __restrict__ w,
    const float* __restrict__ qa, const float* __restrict__ qb,
    const float* __restrict__ ka, const float* __restrict__ kb,
    const float* __restrict__ va, const float* __restrict__ vb,
    bf16_t* __restrict__ wfT)
{
  __shared__ float tile[64][65];
  const int t  = threadIdx.x;
  const int n0 = blockIdx.x * 64;
  const int k0 = blockIdx.y * 64;
  #pragma unroll
  for (int it = 0; it < 4; ++it) {
    const int kr = (t >> 4) + it * 16;
    const float4 vv = *(const float4*)(w + (size_t)(k0 + kr) * 17536 + n0 + (t & 15) * 4);
    tile[kr][(t & 15) * 4 + 0] = vv.x;
    tile[kr][(t & 15) * 4 + 1] = vv.y;
    tile[kr][(t & 15) * 4 + 2] = vv.z;
    tile[kr][(t & 15) * 4 + 3] = vv.w;
  }
  __syncthreads();
  const float* la = nullptr; const float* lb = nullptr;
  int nbo = 0, ldlb = 0;
  if (n0 < 1024)      { la = qa; lb = qb; nbo = n0;        ldlb = 1024; }
  else if (n0 < 1088) { la = ka; lb = kb; nbo = n0 - 1024; ldlb = 64;   }
  else if (n0 < 1152) { la = va; lb = vb; nbo = n0 - 1088; ldlb = 64;   }
  #pragma unroll
  for (int it = 0; it < 2; ++it) {
    const int nl = (t >> 3) + it * 32;
    const int kl = (t & 7) * 8;
    float vals[8];
    #pragma unroll
    for (int e = 0; e < 8; ++e) vals[e] = tile[kl + e][nl];
    if (la) {
      float bc[8];
      #pragma unroll
      for (int r = 0; r < 8; ++r) bc[r] = lb[r * ldlb + nbo + nl];
      #pragma unroll
      for (int e = 0; e < 8; ++e) {
        const float* ar = la + (size_t)(k0 + kl + e) * 8;
        float d = 0.f;
        #pragma unroll
        for (int r = 0; r < 8; ++r) d += ar[r] * bc[r];
        vals[e] += d;
      }
    }
    bf16x8 o;
    #pragma unroll
    for (int e = 0; e < 8; ++e) o[e] = (bf16_t)vals[e];
    *(bf16x8*)(wfT + (size_t)(n0 + nl) * 2048 + k0 + kl) = o;
  }
}

// ---------------------------------------------------------------------------
// Build w2T (2048 x 9216 bf16): cols [0,8192) = w_ff_out^T,
// cols [8192,9216) = (w_attn_out + lora_o_a@lora_o_b)^T.
// ---------------------------------------------------------------------------
__global__ __launch_bounds__(256) void transpose_w2_kernel(
    const float* __restrict__ wff,   // 8192 x 2048
    const float* __restrict__ watt,  // 1024 x 2048
    const float* __restrict__ oa, const float* __restrict__ ob,
    bf16_t* __restrict__ w2T)
{
  __shared__ float tile[64][65];
  const int t  = threadIdx.x;
  const int n0 = blockIdx.x * 64;
  const int k0 = blockIdx.y * 64;          // 0..9152
  const bool isatt = (k0 >= 8192);
  const float* src = isatt ? (watt + (size_t)(k0 - 8192) * 2048)
                           : (wff + (size_t)k0 * 2048);
  #pragma unroll
  for (int it = 0; it < 4; ++it) {
    const int kr = (t >> 4) + it * 16;
    const float4 vv = *(const float4*)(src + (size_t)kr * 2048 + n0 + (t & 15) * 4);
    tile[kr][(t & 15) * 4 + 0] = vv.x;
    tile[kr][(t & 15) * 4 + 1] = vv.y;
    tile[kr][(t & 15) * 4 + 2] = vv.z;
    tile[kr][(t & 15) * 4 + 3] = vv.w;
  }
  __syncthreads();
  #pragma unroll
  for (int it = 0; it < 2; ++it) {
    const int nl = (t >> 3) + it * 32;
    const int kl = (t & 7) * 8;
    float vals[8];
    #pragma unroll
    for (int e = 0; e < 8; ++e) vals[e] = tile[kl + e][nl];
    if (isatt) {
      float bc[8];
      #pragma unroll
      for (int r = 0; r < 8; ++r) bc[r] = ob[r * 2048 + n0 + nl];
      #pragma unroll
      for (int e = 0; e < 8; ++e) {
        const float* ar = oa + (size_t)(k0 - 8192 + kl + e) * 8;
        float d = 0.f;
        #pragma unroll
        for (int r = 0; r < 8; ++r) d += ar[r] * bc[r];
        vals[e] += d;
      }
    }
    bf16x8 o;
    #pragma unroll
    for (int e = 0; e < 8; ++e) o[e] = (bf16_t)vals[e];
    *(bf16x8*)(w2T + (size_t)(n0 + nl) * 9216 + k0 + kl) = o;
  }
}

// ---------------------------------------------------------------------------
// Single-B GEMM core: C[128x128] += A * BT^T (16 MFMA/barrier).  (qkv only)
// ---------------------------------------------------------------------------
__device__ __forceinline__ void gemm_core_128x128(
    const bf16_t* __restrict__ A, int ldA, int m0,
    const bf16_t* __restrict__ BT, int ldB, int n0,
    int K, bf16_t* As, bf16_t* Bs, f32x4* acc)
{
  const int t = threadIdx.x;
  const int wave = t >> 6;
  const int lane = t & 63;
  const int quad = lane >> 4;
  const int ln15 = lane & 15;
  const int wm = wave & 1, wn = wave >> 1;

  const bf16_t* gA = A + (size_t)(m0 + (t >> 2)) * ldA + ((t & 3) << 3);
  const bf16_t* gB = BT + (size_t)(n0 + (t >> 2)) * ldB + ((t & 3) << 3);
  char* lA = (char*)As + wave * 1024;
  char* lB = (char*)Bs + wave * 1024;
  const size_t sA64 = (size_t)64 * ldA;
  const size_t sB64 = (size_t)64 * ldB;
  const int aoff = (wm * 64 + ln15) * 32 + quad * 8;
  const int boff = (wn * 64 + ln15) * 32 + quad * 8;

  for (int kt = 0; kt < K; kt += 32) {
    gload_lds16(gA,        lA);
    gload_lds16(gA + sA64, lA + 4096);
    gload_lds16(gB,        lB);
    gload_lds16(gB + sB64, lB + 4096);
    gA += 32;
    gB += 32;
    __syncthreads();
    bf16x8 a0 = *(const bf16x8*)(As + aoff);
    bf16x8 a1 = *(const bf16x8*)(As + aoff + 512);
    bf16x8 a2 = *(const bf16x8*)(As + aoff + 1024);
    bf16x8 a3 = *(const bf16x8*)(As + aoff + 1536);
    bf16x8 b0 = *(const bf16x8*)(Bs + boff);
    bf16x8 b1 = *(const bf16x8*)(Bs + boff + 512);
    bf16x8 b2 = *(const bf16x8*)(Bs + boff + 1024);
    bf16x8 b3 = *(const bf16x8*)(Bs + boff + 1536);
    acc[0]  = mfma16(a0, b0, acc[0]);
    acc[1]  = mfma16(a0, b1, acc[1]);
    acc[2]  = mfma16(a0, b2, acc[2]);
    acc[3]  = mfma16(a0, b3, acc[3]);
    acc[4]  = mfma16(a1, b0, acc[4]);
    acc[5]  = mfma16(a1, b1, acc[5]);
    acc[6]  = mfma16(a1, b2, acc[6]);
    acc[7]  = mfma16(a1, b3, acc[7]);
    acc[8]  = mfma16(a2, b0, acc[8]);
    acc[9]  = mfma16(a2, b1, acc[9]);
    acc[10] = mfma16(a2, b2, acc[10]);
    acc[11] = mfma16(a2, b3, acc[11]);
    acc[12] = mfma16(a3, b0, acc[12]);
    acc[13] = mfma16(a3, b1, acc[13]);
    acc[14] = mfma16(a3, b2, acc[14]);
    acc[15] = mfma16(a3, b3, acc[15]);
    __syncthreads();
  }
}

// ---------------------------------------------------------------------------
// Dual-B GEMM core: one A tile, two B tiles, 32 MFMA/barrier.  (qkv only)
// ---------------------------------------------------------------------------
__device__ __forceinline__ void gemm_core_dual(
    const bf16_t* gA, const bf16_t* gB0, const bf16_t* gB1,
    int ldA, int ldB, int K,
    bf16_t* As, bf16_t* B0s, bf16_t* B1s,
    f32x4* acc0, f32x4* acc1)
{
  const int t = threadIdx.x;
  const int wave = t >> 6;
  const int lane = t & 63;
  const int quad = lane >> 4;
  const int ln15 = lane & 15;
  const int wm = wave & 1, wn = wave >> 1;

  char* lA = (char*)As + wave * 1024;
  char* l0 = (char*)B0s + wave * 1024;
  char* l1 = (char*)B1s + wave * 1024;
  const size_t sA64 = (size_t)64 * ldA;
  const size_t sB64 = (size_t)64 * ldB;
  const int aoff = (wm * 64 + ln15) * 32 + quad * 8;
  const int boff = (wn * 64 + ln15) * 32 + quad * 8;

  for (int kt = 0; kt < K; kt += 32) {
    gload_lds16(gA,         lA);
    gload_lds16(gA + sA64,  lA + 4096);
    gload_lds16(gB0,        l0);
    gload_lds16(gB0 + sB64, l0 + 4096);
    gload_lds16(gB1,        l1);
    gload_lds16(gB1 + sB64, l1 + 4096);
    gA += 32; gB0 += 32; gB1 += 32;
    __syncthreads();
    bf16x8 a0 = *(const bf16x8*)(As + aoff);
    bf16x8 a1 = *(const bf16x8*)(As + aoff + 512);
    bf16x8 a2 = *(const bf16x8*)(As + aoff + 1024);
    bf16x8 a3 = *(const bf16x8*)(As + aoff + 1536);
    bf16x8 p0 = *(const bf16x8*)(B0s + boff);
    bf16x8 p1 = *(const bf16x8*)(B0s + boff + 512);
    bf16x8 p2 = *(const bf16x8*)(B0s + boff + 1024);
    bf16x8 p3 = *(const bf16x8*)(B0s + boff + 1536);
    bf16x8 q0 = *(const bf16x8*)(B1s + boff);
    bf16x8 q1 = *(const bf16x8*)(B1s + boff + 512);
    bf16x8 q2 = *(const bf16x8*)(B1s + boff + 1024);
    bf16x8 q3 = *(const bf16x8*)(B1s + boff + 1536);
    acc0[0]  = mfma16(a0, p0, acc0[0]);
    acc0[1]  = mfma16(a0, p1, acc0[1]);
    acc0[2]  = mfma16(a0, p2, acc0[2]);
    acc0[3]  = mfma16(a0, p3, acc0[3]);
    acc1[0]  = mfma16(a0, q0, acc1[0]);
    acc1[1]  = mfma16(a0, q1, acc1[1]);
    acc1[2]  = mfma16(a0, q2, acc1[2]);
    acc1[3]  = mfma16(a0, q3, acc1[3]);
    acc0[4]  = mfma16(a1, p0, acc0[4]);
    acc0[5]  = mfma16(a1, p1, acc0[5]);
    acc0[6]  = mfma16(a1, p2, acc0[6]);
    acc0[7]  = mfma16(a1, p3, acc0[7]);
    acc1[4]  = mfma16(a1, q0, acc1[4]);
    acc1[5]  = mfma16(a1, q1, acc1[5]);
    acc1[6]  = mfma16(a1, q2, acc1[6]);
    acc1[7]  = mfma16(a1, q3, acc1[7]);
    acc0[8]  = mfma16(a2, p0, acc0[8]);
    acc0[9]  = mfma16(a2, p1, acc0[9]);
    acc0[10] = mfma16(a2, p2, acc0[10]);
    acc0[11] = mfma16(a2, p3, acc0[11]);
    acc1[8]  = mfma16(a2, q0, acc1[8]);
    acc1[9]  = mfma16(a2, q1, acc1[9]);
    acc1[10] = mfma16(a2, q2, acc1[10]);
    acc1[11] = mfma16(a2, q3, acc1[11]);
    acc0[12] = mfma16(a3, p0, acc0[12]);
    acc0[13] = mfma16(a3, p1, acc0[13]);
    acc0[14] = mfma16(a3, p2, acc0[14]);
    acc0[15] = mfma16(a3, p3, acc0[15]);
    acc1[12] = mfma16(a3, q0, acc1[12]);
    acc1[13] = mfma16(a3, q1, acc1[13]);
    acc1[14] = mfma16(a3, q2, acc1[14]);
    acc1[15] = mfma16(a3, q3, acc1[15]);
    __syncthreads();
  }
}

// ---------------------------------------------------------------------------
// GEMM1a (qkv cols 0..1151), RoPE + layout fused.
// ---------------------------------------------------------------------------
__global__ __launch_bounds__(256, 2) void gemm1_qkv_kernel(
    const bf16_t* __restrict__ xn, const bf16_t* __restrict__ wfT,
    bf16_t* __restrict__ Q, bf16_t* __restrict__ K, bf16_t* __restrict__ Vt)
{
  __shared__ __align__(16) bf16_t As[128 * 32];
  __shared__ __align__(16) bf16_t B0s[128 * 32];
  __shared__ __align__(16) bf16_t B1s[128 * 32];
  const int m0 = blockIdx.x * 128;
  const int y = blockIdx.y;
  const int t = threadIdx.x;
  const int wave = t >> 6, lane = t & 63;
  const int quad = lane >> 4, ln15 = lane & 15;
  const int wm = wave & 1, wn = wave >> 1;

  const int rb = m0 + wm * 64 + quad * 4;
  const float invf0 = exp2f(-(float)ln15 * (LOG2_10K / 32.0f));
  const float invf1 = exp2f(-(float)(16 + ln15) * (LOG2_10K / 32.0f));

  if (y < 4) {
    const bf16_t* gA  = xn  + (size_t)(m0 + (t >> 2)) * 2048 + ((t & 3) << 3);
    const bf16_t* gB0 = wfT + (size_t)(y * 256 + (t >> 2)) * 2048 + ((t & 3) << 3);
    const bf16_t* gB1 = wfT + (size_t)(y * 256 + 128 + (t >> 2)) * 2048 + ((t & 3) << 3);
    f32x4 acc0[16], acc1[16];
    #pragma unroll
    for (int f = 0; f < 16; ++f) {
      acc0[f] = (f32x4){0.f, 0.f, 0.f, 0.f};
      acc1[f] = (f32x4){0.f, 0.f, 0.f, 0.f};
    }
    gemm_core_dual(gA, gB0, gB1, 2048, 2048, 2048, As, B0s, B1s, acc0, acc1);
    #pragma unroll
    for (int half = 0; half < 2; ++half) {
      const f32x4* acc = half ? acc1 : acc0;
      const int hd = y * 4 + half * 2 + wn;
      #pragma unroll
      for (int i = 0; i < 4; ++i) {
        #pragma unroll
        for (int rr = 0; rr < 4; ++rr) {
          const int row = rb + i * 16 + rr;
          const int b = row >> 11, n = row & 2047;
          const float fn = (float)n;
          float s0, c0, s1, c1;
          __sincosf(fn * invf0, &s0, &c0);
          __sincosf(fn * invf1, &s1, &c1);
          float vals[4];
          #pragma unroll
          for (int j = 0; j < 4; ++j) vals[j] = acc[i * 4 + j][rr];
          #pragma unroll
          for (int j = 0; j < 4; ++j) {
            const float rot = (j < 2) ? -vals[j + 2] : vals[j - 2];
            const float c = (j & 1) ? c1 : c0;
            const float s = (j & 1) ? s1 : s0;
            const float o = (vals[j] * c + rot * s) * 0.125f;
            Q[(((size_t)b * 16 + hd) * 2048 + n) * 64 + j * 16 + ln15] = (bf16_t)o;
          }
        }
      }
    }
  } else {
    f32x4 acc[16];
    #pragma unroll
    for (int f = 0; f < 16; ++f) acc[f] = (f32x4){0.f, 0.f, 0.f, 0.f};
    gemm_core_128x128(xn, 2048, m0, wfT, 2048, 1024, 2048, As, B0s, acc);
    const bool is_k = (wn == 0);
    #pragma unroll
    for (int i = 0; i < 4; ++i) {
      #pragma unroll
      for (int rr = 0; rr < 4; ++rr) {
        const int row = rb + i * 16 + rr;
        const int b = row >> 11, n = row & 2047;
        float vals[4];
        #pragma unroll
        for (int j = 0; j < 4; ++j) vals[j] = acc[i * 4 + j][rr];
        if (is_k) {
          const float fn = (float)n;
          float s0, c0, s1, c1;
          __sincosf(fn * invf0, &s0, &c0);
          __sincosf(fn * invf1, &s1, &c1);
          #pragma unroll
          for (int j = 0; j < 4; ++j) {
            const float rot = (j < 2) ? -vals[j + 2] : vals[j - 2];
            const float c = (j & 1) ? c1 : c0;
            const float s = (j & 1) ? s1 : s0;
            K[((size_t)b * 2048 + n) * 64 + j * 16 + ln15] = (bf16_t)(vals[j] * c + rot * s);
          }
        } else {
          #pragma unroll
          for (int j = 0; j < 4; ++j)
            Vt[((size_t)b * 64 + j * 16 + ln15) * 2048 + n] = (bf16_t)vals[j];
        }
      }
    }
  }
}

// ===========================================================================
// Register-prefetch pipelined cores (R5 schedule, R6 waitcnt intrinsics)
// ===========================================================================

#define FF_STG() {                                                           \
    char* lA_ = lds + sst + w * 1024;                                        \
    gload_lds16(gA, lA_);                                                    \
    gload_lds16(gA + (size_t)128 * 2048, lA_ + 8192);                        \
    char* lB_ = lds + 65536 + sst + w * 1024;                                \
    gload_lds16(gB0, lB_);                                                   \
    gload_lds16(gB1, lB_ + 8192);                                            \
    gA += 32; gB0 += 32; gB1 += 32;                                          \
    sst = (sst + 16384) & 65535; }

#define FF_RD(DA, DB) {                                                      \
    _Pragma("unroll")                                                        \
    for (int mf_ = 0; mf_ < 8; ++mf_)                                        \
      DA[mf_] = *(const bf16x8*)(lds + srd + wm * 8192 + mf_ * 1024 + ro);   \
    _Pragma("unroll")                                                        \
    for (int nf_ = 0; nf_ < 4; ++nf_)                                        \
      DB[nf_] = *(const bf16x8*)(lds + 65536 + srd + wn * 4096 + nf_ * 1024 + ro); \
    srd = (srd + 16384) & 65535;                                             \
    __builtin_amdgcn_sched_barrier(0); }

#define FF_MM(SA, SB) {                                                      \
    __builtin_amdgcn_s_setprio(1);                                           \
    _Pragma("unroll")                                                        \
    for (int mf_ = 0; mf_ < 8; ++mf_) {                                      \
      _Pragma("unroll")                                                      \
      for (int nf_ = 0; nf_ < 4; ++nf_)                                      \
        acc[mf_][nf_] = mfma16(SA[mf_], SB[nf_], acc[mf_][nf_]);             \
    }                                                                        \
    __builtin_amdgcn_s_setprio(0); }

#define FF_SYNC4() { WAITCNT_VM(4); __builtin_amdgcn_s_barrier(); }

// ---------------------------------------------------------------------------
// GEMM1b (ff): BM=256, B = 128 gate + 128 x rows interleaved (16-row), BK=32,
// 512 thr (8 waves 2Mx4N). 4-slot LDS ring (128 KB), reg-prefetch pipeline.
// ---------------------------------------------------------------------------
__global__ __launch_bounds__(512, 2) void gemm1_ff_kernel(
    const bf16_t* __restrict__ xn, const bf16_t* __restrict__ wfT,
    bf16_t* __restrict__ A2)
{
  __shared__ __align__(16) char lds[131072];
  const int m0 = blockIdx.x * 256;
  const int c0 = blockIdx.y * 128;
  const int t = threadIdx.x;
  const int w = t >> 6, lane = t & 63;
  const int quad = lane >> 4, ln15 = lane & 15;
  const int wm = w & 1, wn = w >> 1;          // 2 x 4 wave grid

  const int p  = w * 64 + lane;
  const int r  = p >> 2;
  const int cl = (p & 3) ^ ((r >> 1) & 3);
  const bf16_t* gA = xn + (size_t)(m0 + r) * 2048 + cl * 8;
  const int r2 = r + 128;
  const int cm0 = c0 + ((r  >> 5) << 4) + (r  & 15);
  const int cm1 = c0 + ((r2 >> 5) << 4) + (r2 & 15);
  const int wr0 = ((r  >> 4) & 1) ? (1152 + cm0) : (9344 + cm0);
  const int wr1 = ((r2 >> 4) & 1) ? (1152 + cm1) : (9344 + cm1);
  const bf16_t* gB0 = wfT + (size_t)wr0 * 2048 + cl * 8;
  const bf16_t* gB1 = wfT + (size_t)wr1 * 2048 + cl * 8;

  const int ro = ln15 * 64 + ((quad ^ ((ln15 >> 1) & 3)) * 16);

  f32x4 acc[8][4];
  #pragma unroll
  for (int mf = 0; mf < 8; ++mf)
    #pragma unroll
    for (int nf = 0; nf < 4; ++nf)
      acc[mf][nf] = (f32x4){0.f, 0.f, 0.f, 0.f};

  int sst = 0, srd = 0;
  // prologue: stage tiles 0,1,2 (12 loads)
  #pragma unroll
  for (int pt = 0; pt < 3; ++pt) FF_STG();
  // tiles 0,1 complete (oldest 8 of 12 retired); tile 2 still in flight
  FF_SYNC4();

  bf16x8 fA[8], fB[4], nA[8], nB[4];
  FF_RD(fA, fB);                         // frags(0); srd -> 16384

  // main loop: tt = 0..60 (uniform). invariant at top: only tile tt+2 in flight
  for (int i = 0; i < 30; ++i) {
    FF_STG(); FF_RD(nA, nB); FF_MM(fA, fB); FF_SYNC4();   // tt even
    FF_STG(); FF_RD(fA, fB); FF_MM(nA, nB); FF_SYNC4();   // tt odd
  }
  FF_STG(); FF_RD(nA, nB); FF_MM(fA, fB); FF_SYNC4();     // tt=60 (stages 63)
  // tail: tiles 61..63
  FF_RD(fA, fB); FF_MM(nA, nB);                           // tt=61, reads 62
  WAITCNT_VM(0);
  __builtin_amdgcn_s_barrier();
  FF_RD(nA, nB); FF_MM(fA, fB);                           // tt=62, reads 63
  FF_MM(nA, nB);                                          // tt=63

  // epilogue: silu(gate)*x -> A2 cols [0,8192)
  const int row0 = m0 + wm * 128 + quad * 4;
  const int col0 = c0 + wn * 32 + ln15;
  #pragma unroll
  for (int mf = 0; mf < 8; ++mf)
    #pragma unroll
    for (int rr = 0; rr < 4; ++rr) {
      bf16_t* dst = A2 + (size_t)(row0 + mf * 16 + rr) * 9216 + col0;
      #pragma unroll
      for (int j = 0; j < 2; ++j) {
        const float g  = acc[mf][2 * j][rr];
        const float xv = acc[mf][2 * j + 1][rr];
        dst[j * 16] = (bf16_t)(xv * (g / (1.f + exp2f(-g * LOG2E))));
      }
    }
}

#define G2_STG() {                                                           \
    char* lA_ = lds + sstA + w * 1024;                                       \
    gload_lds16(gA, lA_);                                                    \
    gload_lds16(gA + (size_t)128 * 9216, lA_ + 8192);                        \
    gload_lds16(gB, lds + 65536 + sstB + w * 1024);                          \
    gA += 32; gB += 32;                                                      \
    sstA = (sstA + 16384) & 65535;                                           \
    sstB = (sstB + 8192) & 32767; }

#define G2_RD(DA, DB) {                                                      \
    _Pragma("unroll")                                                        \
    for (int mf_ = 0; mf_ < 4; ++mf_)                                        \
      DA[mf_] = *(const bf16x8*)(lds + srdA + wm * 4096 + mf_ * 1024 + ro);  \
    _Pragma("unroll")                                                        \
    for (int nf_ = 0; nf_ < 4; ++nf_)                                        \
      DB[nf_] = *(const bf16x8*)(lds + 65536 + srdB + wn * 4096 + nf_ * 1024 + ro); \
    srdA = (srdA + 16384) & 65535;                                           \
    srdB = (srdB + 8192) & 32767;                                            \
    __builtin_amdgcn_sched_barrier(0); }

#define G2_MM(SA, SB) {                                                      \
    __builtin_amdgcn_s_setprio(1);                                           \
    _Pragma("unroll")                                                        \
    for (int mf_ = 0; mf_ < 4; ++mf_) {                                      \
      _Pragma("unroll")                                                      \
      for (int nf_ = 0; nf_ < 4; ++nf_)                                      \
        acc[mf_][nf_] = mfma16(SA[mf_], SB[nf_], acc[mf_][nf_]);             \
    }                                                                        \
    __builtin_amdgcn_s_setprio(0); }

#define G2_SYNC3() { WAITCNT_VM(3); __builtin_amdgcn_s_barrier(); }

// ---------------------------------------------------------------------------
// GEMM2: out = A2(4096x9216) @ w2T^T. BM=256/BN=128, BK=32, 512 thr (4Mx2N).
// Grid 16x16=256 blocks, no split-K, direct f32 stores. 4-slot ring (96 KB),
// reg-prefetch pipeline.
// ---------------------------------------------------------------------------
__global__ __launch_bounds__(512, 2) void gemm2_kernel(
    const bf16_t* __restrict__ A2, const bf16_t* __restrict__ w2T,
    float* __restrict__ out)
{
  __shared__ __align__(16) char lds[98304];
  const int m0 = blockIdx.x * 256;
  const int n0 = blockIdx.y * 128;
  const int t = threadIdx.x;
  const int w = t >> 6, lane = t & 63;
  const int quad = lane >> 4, ln15 = lane & 15;
  const int wm = w & 3, wn = w >> 2;          // 4 x 2 wave grid

  const int p  = w * 64 + lane;
  const int r  = p >> 2;
  const int cl = (p & 3) ^ ((r >> 1) & 3);
  const bf16_t* gA = A2  + (size_t)(m0 + r) * 9216 + cl * 8;
  const bf16_t* gB = w2T + (size_t)(n0 + r) * 9216 + cl * 8;

  const int ro = ln15 * 64 + ((quad ^ ((ln15 >> 1) & 3)) * 16);

  f32x4 acc[4][4];
  #pragma unroll
  for (int mf = 0; mf < 4; ++mf)
    #pragma unroll
    for (int nf = 0; nf < 4; ++nf)
      acc[mf][nf] = (f32x4){0.f, 0.f, 0.f, 0.f};

  int sstA = 0, sstB = 0, srdA = 0, srdB = 0;
  #pragma unroll
  for (int pt = 0; pt < 3; ++pt) G2_STG();
  // 9 loads out; wait -> 3 remain: tiles 0,1 complete
  G2_SYNC3();

  bf16x8 fA[4], fB[4], nA[4], nB[4];
  G2_RD(fA, fB);                          // frags(0)

  // main loop: tt = 0..284 (uniform)
  for (int i = 0; i < 142; ++i) {
    G2_STG(); G2_RD(nA, nB); G2_MM(fA, fB); G2_SYNC3();
    G2_STG(); G2_RD(fA, fB); G2_MM(nA, nB); G2_SYNC3();
  }
  G2_STG(); G2_RD(nA, nB); G2_MM(fA, fB); G2_SYNC3();     // tt=284 (stages 287)
  // tail: 285..287
  G2_RD(fA, fB); G2_MM(nA, nB);                           // tt=285, reads 286
  WAITCNT_VM(0);
  __builtin_amdgcn_s_barrier();
  G2_RD(nA, nB); G2_MM(fA, fB);                           // tt=286, reads 287
  G2_MM(nA, nB);                                          // tt=287

  const int row0 = m0 + wm * 64 + quad * 4;
  const int col0 = n0 + wn * 64 + ln15;
  #pragma unroll
  for (int mf = 0; mf < 4; ++mf)
    #pragma unroll
    for (int rr = 0; rr < 4; ++rr) {
      float* dst = out + (size_t)(row0 + mf * 16 + rr) * 2048 + col0;
      #pragma unroll
      for (int nf = 0; nf < 4; ++nf)
        dst[nf * 16] = acc[mf][nf][rr];
    }
}

// ---------------------------------------------------------------------------
// Causal MQA flash attention -> A2[:, 8192 + h*64 + d]. Paired Q-tiles
// (qt = p and 31-p), grid (16,32), 512 blocks, LDS 32 KB.
// ---------------------------------------------------------------------------
__global__ __launch_bounds__(256, 2) void attn_kernel(
    const bf16_t* __restrict__ Q, const bf16_t* __restrict__ Kg_,
    const bf16_t* __restrict__ Vt, bf16_t* __restrict__ A2)
{
  __shared__ __align__(16) bf16_t Qs[64 * 64];
  __shared__ __align__(16) bf16_t Ks[64 * 64];
  __shared__ __align__(16) bf16_t Vs[64 * 64];
  __shared__ __align__(16) bf16_t Ps[64 * 64];
  const int pidx = blockIdx.x, bh = blockIdx.y;
  const int b = bh >> 4, h = bh & 15;
  const int t = threadIdx.x;
  const int wave = t >> 6, lane = t & 63;
  const int quad = lane >> 4, ln15 = lane & 15;

  const bf16_t* Kg = Kg_ + (size_t)b * 2048 * 64;
  const bf16_t* Vg = Vt + (size_t)b * 64 * 2048;

  for (int hlf = 0; hlf < 2; ++hlf) {
    const int qt = hlf ? (31 - pidx) : pidx;
    const int qm0 = qt * 64;
    const bf16_t* Qg = Q + ((size_t)bh * 2048 + qm0) * 64;

    { // stage Q tile (8 KB, 2 rounds)
      const bf16_t* g = Qg + (size_t)(t >> 3) * 64 + ((t & 7) << 3);
      char* l = (char*)Qs + wave * 1024;
      gload_lds16(g,           l);
      gload_lds16(g + 32 * 64, l + 4096);
    }

    float mstate[4], lstate[4];
    f32x4 o_acc[4];
    #pragma unroll
    for (int rr = 0; rr < 4; ++rr) { mstate[rr] = -1e30f; lstate[rr] = 0.f; }
    #pragma unroll
    for (int jd = 0; jd < 4; ++jd) o_acc[jd] = (f32x4){0.f, 0.f, 0.f, 0.f};

    const int njt = qt + 1;
    for (int jt = 0; jt < njt; ++jt) {
      { // stage K, V tiles (8 KB each)
        const bf16_t* kg = Kg + (size_t)(jt * 64 + (t >> 3)) * 64 + ((t & 7) << 3);
        char* lk = (char*)Ks + wave * 1024;
        gload_lds16(kg,           lk);
        gload_lds16(kg + 32 * 64, lk + 4096);
        const bf16_t* vg = Vg + (size_t)(t >> 3) * 2048 + jt * 64 + ((t & 7) << 3);
        char* lv = (char*)Vs + wave * 1024;
        gload_lds16(vg,                   lv);
        gload_lds16(vg + (size_t)32*2048, lv + 4096);
      }
      __syncthreads();

      f32x4 sA[4];
      #pragma unroll
      for (int j = 0; j < 4; ++j) sA[j] = (f32x4){0.f, 0.f, 0.f, 0.f};
      #pragma unroll
      for (int ks = 0; ks < 2; ++ks) {
        bf16x8 aq = *(const bf16x8*)(Qs + (wave * 16 + ln15) * 64 + ks * 32 + quad * 8);
        #pragma unroll
        for (int j = 0; j < 4; ++j) {
          bf16x8 bk = *(const bf16x8*)(Ks + (j * 16 + ln15) * 64 + ks * 32 + quad * 8);
          sA[j] = mfma16(aq, bk, sA[j]);
        }
      }

      const bool needmask = (jt * 64 + 63 > qm0 + wave * 16);
      const int row0 = qm0 + wave * 16 + quad * 4;
      float alpha[4];
      #pragma unroll
      for (int rr = 0; rr < 4; ++rr) {
        const int rowg = row0 + rr;
        if (needmask) {
          #pragma unroll
          for (int j = 0; j < 4; ++j) {
            const int colg = jt * 64 + j * 16 + ln15;
            if (colg > rowg) sA[j][rr] = -1e30f;
          }
        }
        float mx = fmaxf(fmaxf(sA[0][rr], sA[1][rr]),
                         fmaxf(sA[2][rr], sA[3][rr]));
        mx = fmaxf(mx, __shfl_xor(mx, 1));
        mx = fmaxf(mx, __shfl_xor(mx, 2));
        mx = fmaxf(mx, __shfl_xor(mx, 4));
        mx = fmaxf(mx, __shfl_xor(mx, 8));
        const float mold = mstate[rr];
        const float mnew = fmaxf(mold, mx);
        const float al = exp2f((mold - mnew) * LOG2E);
        float rsum = 0.f;
        #pragma unroll
        for (int j = 0; j < 4; ++j) {
          const float p = exp2f((sA[j][rr] - mnew) * LOG2E);
          sA[j][rr] = p;
          rsum += p;
        }
        rsum += __shfl_xor(rsum, 1);
        rsum += __shfl_xor(rsum, 2);
        rsum += __shfl_xor(rsum, 4);
        rsum += __shfl_xor(rsum, 8);
        lstate[rr] = lstate[rr] * al + rsum;
        mstate[rr] = mnew;
        alpha[rr] = al;
      }
      #pragma unroll
      for (int jd = 0; jd < 4; ++jd)
        #pragma unroll
        for (int rr = 0; rr < 4; ++rr)
          o_acc[jd][rr] *= alpha[rr];
      #pragma unroll
      for (int j = 0; j < 4; ++j)
        #pragma unroll
        for (int rr = 0; rr < 4; ++rr)
          Ps[wave * 1024 + (quad * 4 + rr) * 64 + j * 16 + ln15] = (bf16_t)sA[j][rr];

      #pragma unroll
      for (int ks = 0; ks < 2; ++ks) {
        bf16x8 ap = *(const bf16x8*)(Ps + wave * 1024 + ln15 * 64 + ks * 32 + quad * 8);
        #pragma unroll
        for (int jd = 0; jd < 4; ++jd) {
          bf16x8 bv = *(const bf16x8*)(Vs + (jd * 16 + ln15) * 64 + ks * 32 + quad * 8);
          o_acc[jd] = mfma16(ap, bv, o_acc[jd]);
        }
      }
      __syncthreads();
    }

    const int row0 = qm0 + wave * 16 + quad * 4;
    #pragma unroll
    for (int rr = 0; rr < 4; ++rr) {
      const float inv = 1.f / lstate[rr];
      bf16_t* dst = A2 + ((size_t)b * 2048 + row0 + rr) * 9216 + 8192 + h * 64 + ln15;
      #pragma unroll
      for (int jd = 0; jd < 4; ++jd)
        dst[jd * 16] = (bf16_t)(o_acc[jd][rr] * inv);
    }
  }
}

// ---------------------------------------------------------------------------
extern "C" void kernel_launch(void* const* d_in, const int* in_sizes, int n_in,
                              void* d_out, int out_size, void* d_ws, size_t ws_size,
                              hipStream_t stream)
{
  const float* x      = (const float*)d_in[0];
  const float* gamma  = (const float*)d_in[1];
  const float* wfused = (const float*)d_in[2];
  const float* watt   = (const float*)d_in[3];
  const float* wff    = (const float*)d_in[4];
  const float* qa     = (const float*)d_in[5];
  const float* qb     = (const float*)d_in[6];
  const float* ka     = (const float*)d_in[7];
  const float* kb     = (const float*)d_in[8];
  const float* va     = (const float*)d_in[9];
  const float* vb     = (const float*)d_in[10];
  const float* oa     = (const float*)d_in[11];
  const float* ob     = (const float*)d_in[12];
  float* out = (float*)d_out;

  char* ws = (char*)d_ws;
  bf16_t* xn  = (bf16_t*)(ws);                    // 16,777,216
  bf16_t* wfT = (bf16_t*)(ws + 16777216);         // 71,827,456
  bf16_t* w2T = (bf16_t*)(ws + 88604672);         // 37,748,736
  bf16_t* A2  = (bf16_t*)(ws + 126353408);        // 75,497,472
  bf16_t* Qr  = (bf16_t*)(ws + 201850880);        //  8,388,608
  bf16_t* Kr  = (bf16_t*)(ws + 210239488);        //    524,288
  bf16_t* Vtr = (bf16_t*)(ws + 210763776);        //    524,288

  ln_kernel<<<dim3(4096), dim3(256), 0, stream>>>(x, gamma, xn);
  transpose_wf_kernel<<<dim3(274, 32), dim3(256), 0, stream>>>(
      wfused, qa, qb, ka, kb, va, vb, wfT);
  transpose_w2_kernel<<<dim3(32, 144), dim3(256), 0, stream>>>(
      wff, watt, oa, ob, w2T);
  gemm1_qkv_kernel<<<dim3(32, 5), dim3(256), 0, stream>>>(xn, wfT, Qr, Kr, Vtr);
  gemm1_ff_kernel<<<dim3(16, 64), dim3(512), 0, stream>>>(xn, wfT, A2);
  attn_kernel<<<dim3(16, 32), dim3(256), 0, stream>>>(Qr, Kr, Vtr, A2);
  gemm2_kernel<<<dim3(16, 16), dim3(512), 0, stream>>>(A2, w2T, out);
}

// Round 12
// 871.055 us; speedup vs baseline: 1.0774x; 1.0082x over previous
//
#include <hip/hip_runtime.h>
#include <cstdint>

// ============================================================================
// ParallelTransformerBlock (PaLM-style parallel attn+FF, MQA, RoPE, LoRA)
// B=2, N=2048, DIM=2048, HEADS=16, DIM_HEAD=64 (MQA), FF_INNER=8192, R=8.
//
// R15 = R14 (measured 878.2 us; best composition, reproduced 4x) plus ONE
// zero-risk change: __builtin_amdgcn_s_setprio(1)/(0) around attn's QK^T and
// PV MFMA clusters. Mechanism (m191-class): attn runs 2 independent
// barrier-synced blocks per CU; setprio biases the CU scheduler toward the
// MFMA-entering wave over the other block's staging loads (+4-7% measured on
// attn in that regime; null only for lockstep single-block GEMMs).
// Everything else byte-identical to R14.
// ============================================================================

typedef __bf16 bf16_t;
typedef __bf16 bf16x8 __attribute__((ext_vector_type(8)));
typedef float f32x4 __attribute__((ext_vector_type(4)));

#define LOG2E 1.44269504088896340736f
#define LOG2_10K 13.287712379549449f   // log2(10000)

// s_waitcnt simm16 (gfx9-class): vmcnt[3:0]=bits3:0, expcnt=bits6:4,
// lgkmcnt=bits11:8, vmcnt[5:4]=bits15:14.
#define WAITCNT_VM(N) __builtin_amdgcn_s_waitcnt(0x0F70 | (N))   // vmcnt(N) only

__device__ __forceinline__ void gload_lds16(const void* g, void* l) {
  __builtin_amdgcn_global_load_lds(
      (__attribute__((address_space(1))) void*)(uintptr_t)g,
      (__attribute__((address_space(3))) void*)(uint32_t)(uintptr_t)l,
      16, 0, 0);
}

__device__ __forceinline__ f32x4 mfma16(bf16x8 a, bf16x8 b, f32x4 c) {
  return __builtin_amdgcn_mfma_f32_16x16x32_bf16(a, b, c, 0, 0, 0);
}

// ---------------------------------------------------------------------------
// LayerNorm: one block per token row (4096 rows x 2048)
// ---------------------------------------------------------------------------
__global__ __launch_bounds__(256) void ln_kernel(
    const float* __restrict__ x, const float* __restrict__ gamma,
    bf16_t* __restrict__ xn)
{
  const int row = blockIdx.x;
  const int t = threadIdx.x;
  const float4* xr = (const float4*)(x + (size_t)row * 2048);
  float4 a = xr[t * 2];
  float4 b = xr[t * 2 + 1];
  float s  = a.x + a.y + a.z + a.w + b.x + b.y + b.z + b.w;
  float ss = a.x*a.x + a.y*a.y + a.z*a.z + a.w*a.w
           + b.x*b.x + b.y*b.y + b.z*b.z + b.w*b.w;
  #pragma unroll
  for (int m = 1; m < 64; m <<= 1) {
    s  += __shfl_xor(s, m);
    ss += __shfl_xor(ss, m);
  }
  __shared__ float red[8];
  const int wave = t >> 6, lane = t & 63;
  if (lane == 0) { red[wave] = s; red[4 + wave] = ss; }
  __syncthreads();
  const float stot  = red[0] + red[1] + red[2] + red[3];
  const float sstot = red[4] + red[5] + red[6] + red[7];
  const float mu  = stot * (1.f / 2048.f);
  const float var = sstot * (1.f / 2048.f) - mu * mu;
  const float rs  = rsqrtf(var + 1e-5f);
  float v[8] = {a.x, a.y, a.z, a.w, b.x, b.y, b.z, b.w};
  bf16x8 o;
  #pragma unroll
  for (int e = 0; e < 8; ++e)
    o[e] = (bf16_t)((v[e] - mu) * rs * gamma[t * 8 + e]);
  *(bf16x8*)(xn + (size_t)row * 2048 + t * 8) = o;
}

// ---------------------------------------------------------------------------
// Transpose+convert w_fused (2048 x 17536 f32) -> wfT (17536 x 2048 bf16),
// folding lora_q/k/v into cols [0,1152). 64x64 tiles, LDS pad +1.
// ---------------------------------------------------------------------------
__global__ __launch_bounds__(256) void transpose_wf_kernel(
    const float* __restrict__ w,
    const float* __restrict__ qa, const float* __restrict__ qb,
    const float* __restrict__ ka, const float* __restrict__ kb,
    const float* __restrict__ va, const float* __restrict__ vb,
    bf16_t* __restrict__ wfT)
{
  __shared__ float tile[64][65];
  const int t  = threadIdx.x;
  const int n0 = blockIdx.x * 64;
  const int k0 = blockIdx.y * 64;
  #pragma unroll
  for (int it = 0; it < 4; ++it) {
    const int kr = (t >> 4) + it * 16;
    const float4 vv = *(const float4*)(w + (size_t)(k0 + kr) * 17536 + n0 + (t & 15) * 4);
    tile[kr][(t & 15) * 4 + 0] = vv.x;
    tile[kr][(t & 15) * 4 + 1] = vv.y;
    tile[kr][(t & 15) * 4 + 2] = vv.z;
    tile[kr][(t & 15) * 4 + 3] = vv.w;
  }
  __syncthreads();
  const float* la = nullptr; const float* lb = nullptr;
  int nbo = 0, ldlb = 0;
  if (n0 < 1024)      { la = qa; lb = qb; nbo = n0;        ldlb = 1024; }
  else if (n0 < 1088) { la = ka; lb = kb; nbo = n0 - 1024; ldlb = 64;   }
  else if (n0 < 1152) { la = va; lb = vb; nbo = n0 - 1088; ldlb = 64;   }
  #pragma unroll
  for (int it = 0; it < 2; ++it) {
    const int nl = (t >> 3) + it * 32;
    const int kl = (t & 7) * 8;
    float vals[8];
    #pragma unroll
    for (int e = 0; e < 8; ++e) vals[e] = tile[kl + e][nl];
    if (la) {
      float bc[8];
      #pragma unroll
      for (int r = 0; r < 8; ++r) bc[r] = lb[r * ldlb + nbo + nl];
      #pragma unroll
      for (int e = 0; e < 8; ++e) {
        const float* ar = la + (size_t)(k0 + kl + e) * 8;
        float d = 0.f;
        #pragma unroll
        for (int r = 0; r < 8; ++r) d += ar[r] * bc[r];
        vals[e] += d;
      }
    }
    bf16x8 o;
    #pragma unroll
    for (int e = 0; e < 8; ++e) o[e] = (bf16_t)vals[e];
    *(bf16x8*)(wfT + (size_t)(n0 + nl) * 2048 + k0 + kl) = o;
  }
}

// ---------------------------------------------------------------------------
// Build w2T (2048 x 9216 bf16): cols [0,8192) = w_ff_out^T,
// cols [8192,9216) = (w_attn_out + lora_o_a@lora_o_b)^T.
// ---------------------------------------------------------------------------
__global__ __launch_bounds__(256) void transpose_w2_kernel(
    const float* __restrict__ wff,   // 8192 x 2048
    const float* __restrict__ watt,  // 1024 x 2048
    const float* __restrict__ oa, const float* __restrict__ ob,
    bf16_t* __restrict__ w2T)
{
  __shared__ float tile[64][65];
  const int t  = threadIdx.x;
  const int n0 = blockIdx.x * 64;
  const int k0 = blockIdx.y * 64;          // 0..9152
  const bool isatt = (k0 >= 8192);
  const float* src = isatt ? (watt + (size_t)(k0 - 8192) * 2048)
                           : (wff + (size_t)k0 * 2048);
  #pragma unroll
  for (int it = 0; it < 4; ++it) {
    const int kr = (t >> 4) + it * 16;
    const float4 vv = *(const float4*)(src + (size_t)kr * 2048 + n0 + (t & 15) * 4);
    tile[kr][(t & 15) * 4 + 0] = vv.x;
    tile[kr][(t & 15) * 4 + 1] = vv.y;
    tile[kr][(t & 15) * 4 + 2] = vv.z;
    tile[kr][(t & 15) * 4 + 3] = vv.w;
  }
  __syncthreads();
  #pragma unroll
  for (int it = 0; it < 2; ++it) {
    const int nl = (t >> 3) + it * 32;
    const int kl = (t & 7) * 8;
    float vals[8];
    #pragma unroll
    for (int e = 0; e < 8; ++e) vals[e] = tile[kl + e][nl];
    if (isatt) {
      float bc[8];
      #pragma unroll
      for (int r = 0; r < 8; ++r) bc[r] = ob[r * 2048 + n0 + nl];
      #pragma unroll
      for (int e = 0; e < 8; ++e) {
        const float* ar = oa + (size_t)(k0 - 8192 + kl + e) * 8;
        float d = 0.f;
        #pragma unroll
        for (int r = 0; r < 8; ++r) d += ar[r] * bc[r];
        vals[e] += d;
      }
    }
    bf16x8 o;
    #pragma unroll
    for (int e = 0; e < 8; ++e) o[e] = (bf16_t)vals[e];
    *(bf16x8*)(w2T + (size_t)(n0 + nl) * 9216 + k0 + kl) = o;
  }
}

// ---------------------------------------------------------------------------
// Single-B GEMM core: C[128x128] += A * BT^T (16 MFMA/barrier).  (qkv only)
// ---------------------------------------------------------------------------
__device__ __forceinline__ void gemm_core_128x128(
    const bf16_t* __restrict__ A, int ldA, int m0,
    const bf16_t* __restrict__ BT, int ldB, int n0,
    int K, bf16_t* As, bf16_t* Bs, f32x4* acc)
{
  const int t = threadIdx.x;
  const int wave = t >> 6;
  const int lane = t & 63;
  const int quad = lane >> 4;
  const int ln15 = lane & 15;
  const int wm = wave & 1, wn = wave >> 1;

  const bf16_t* gA = A + (size_t)(m0 + (t >> 2)) * ldA + ((t & 3) << 3);
  const bf16_t* gB = BT + (size_t)(n0 + (t >> 2)) * ldB + ((t & 3) << 3);
  char* lA = (char*)As + wave * 1024;
  char* lB = (char*)Bs + wave * 1024;
  const size_t sA64 = (size_t)64 * ldA;
  const size_t sB64 = (size_t)64 * ldB;
  const int aoff = (wm * 64 + ln15) * 32 + quad * 8;
  const int boff = (wn * 64 + ln15) * 32 + quad * 8;

  for (int kt = 0; kt < K; kt += 32) {
    gload_lds16(gA,        lA);
    gload_lds16(gA + sA64, lA + 4096);
    gload_lds16(gB,        lB);
    gload_lds16(gB + sB64, lB + 4096);
    gA += 32;
    gB += 32;
    __syncthreads();
    bf16x8 a0 = *(const bf16x8*)(As + aoff);
    bf16x8 a1 = *(const bf16x8*)(As + aoff + 512);
    bf16x8 a2 = *(const bf16x8*)(As + aoff + 1024);
    bf16x8 a3 = *(const bf16x8*)(As + aoff + 1536);
    bf16x8 b0 = *(const bf16x8*)(Bs + boff);
    bf16x8 b1 = *(const bf16x8*)(Bs + boff + 512);
    bf16x8 b2 = *(const bf16x8*)(Bs + boff + 1024);
    bf16x8 b3 = *(const bf16x8*)(Bs + boff + 1536);
    acc[0]  = mfma16(a0, b0, acc[0]);
    acc[1]  = mfma16(a0, b1, acc[1]);
    acc[2]  = mfma16(a0, b2, acc[2]);
    acc[3]  = mfma16(a0, b3, acc[3]);
    acc[4]  = mfma16(a1, b0, acc[4]);
    acc[5]  = mfma16(a1, b1, acc[5]);
    acc[6]  = mfma16(a1, b2, acc[6]);
    acc[7]  = mfma16(a1, b3, acc[7]);
    acc[8]  = mfma16(a2, b0, acc[8]);
    acc[9]  = mfma16(a2, b1, acc[9]);
    acc[10] = mfma16(a2, b2, acc[10]);
    acc[11] = mfma16(a2, b3, acc[11]);
    acc[12] = mfma16(a3, b0, acc[12]);
    acc[13] = mfma16(a3, b1, acc[13]);
    acc[14] = mfma16(a3, b2, acc[14]);
    acc[15] = mfma16(a3, b3, acc[15]);
    __syncthreads();
  }
}

// ---------------------------------------------------------------------------
// Dual-B GEMM core: one A tile, two B tiles, 32 MFMA/barrier.  (qkv only)
// ---------------------------------------------------------------------------
__device__ __forceinline__ void gemm_core_dual(
    const bf16_t* gA, const bf16_t* gB0, const bf16_t* gB1,
    int ldA, int ldB, int K,
    bf16_t* As, bf16_t* B0s, bf16_t* B1s,
    f32x4* acc0, f32x4* acc1)
{
  const int t = threadIdx.x;
  const int wave = t >> 6;
  const int lane = t & 63;
  const int quad = lane >> 4;
  const int ln15 = lane & 15;
  const int wm = wave & 1, wn = wave >> 1;

  char* lA = (char*)As + wave * 1024;
  char* l0 = (char*)B0s + wave * 1024;
  char* l1 = (char*)B1s + wave * 1024;
  const size_t sA64 = (size_t)64 * ldA;
  const size_t sB64 = (size_t)64 * ldB;
  const int aoff = (wm * 64 + ln15) * 32 + quad * 8;
  const int boff = (wn * 64 + ln15) * 32 + quad * 8;

  for (int kt = 0; kt < K; kt += 32) {
    gload_lds16(gA,         lA);
    gload_lds16(gA + sA64,  lA + 4096);
    gload_lds16(gB0,        l0);
    gload_lds16(gB0 + sB64, l0 + 4096);
    gload_lds16(gB1,        l1);
    gload_lds16(gB1 + sB64, l1 + 4096);
    gA += 32; gB0 += 32; gB1 += 32;
    __syncthreads();
    bf16x8 a0 = *(const bf16x8*)(As + aoff);
    bf16x8 a1 = *(const bf16x8*)(As + aoff + 512);
    bf16x8 a2 = *(const bf16x8*)(As + aoff + 1024);
    bf16x8 a3 = *(const bf16x8*)(As + aoff + 1536);
    bf16x8 p0 = *(const bf16x8*)(B0s + boff);
    bf16x8 p1 = *(const bf16x8*)(B0s + boff + 512);
    bf16x8 p2 = *(const bf16x8*)(B0s + boff + 1024);
    bf16x8 p3 = *(const bf16x8*)(B0s + boff + 1536);
    bf16x8 q0 = *(const bf16x8*)(B1s + boff);
    bf16x8 q1 = *(const bf16x8*)(B1s + boff + 512);
    bf16x8 q2 = *(const bf16x8*)(B1s + boff + 1024);
    bf16x8 q3 = *(const bf16x8*)(B1s + boff + 1536);
    acc0[0]  = mfma16(a0, p0, acc0[0]);
    acc0[1]  = mfma16(a0, p1, acc0[1]);
    acc0[2]  = mfma16(a0, p2, acc0[2]);
    acc0[3]  = mfma16(a0, p3, acc0[3]);
    acc1[0]  = mfma16(a0, q0, acc1[0]);
    acc1[1]  = mfma16(a0, q1, acc1[1]);
    acc1[2]  = mfma16(a0, q2, acc1[2]);
    acc1[3]  = mfma16(a0, q3, acc1[3]);
    acc0[4]  = mfma16(a1, p0, acc0[4]);
    acc0[5]  = mfma16(a1, p1, acc0[5]);
    acc0[6]  = mfma16(a1, p2, acc0[6]);
    acc0[7]  = mfma16(a1, p3, acc0[7]);
    acc1[4]  = mfma16(a1, q0, acc1[4]);
    acc1[5]  = mfma16(a1, q1, acc1[5]);
    acc1[6]  = mfma16(a1, q2, acc1[6]);
    acc1[7]  = mfma16(a1, q3, acc1[7]);
    acc0[8]  = mfma16(a2, p0, acc0[8]);
    acc0[9]  = mfma16(a2, p1, acc0[9]);
    acc0[10] = mfma16(a2, p2, acc0[10]);
    acc0[11] = mfma16(a2, p3, acc0[11]);
    acc1[8]  = mfma16(a2, q0, acc1[8]);
    acc1[9]  = mfma16(a2, q1, acc1[9]);
    acc1[10] = mfma16(a2, q2, acc1[10]);
    acc1[11] = mfma16(a2, q3, acc1[11]);
    acc0[12] = mfma16(a3, p0, acc0[12]);
    acc0[13] = mfma16(a3, p1, acc0[13]);
    acc0[14] = mfma16(a3, p2, acc0[14]);
    acc0[15] = mfma16(a3, p3, acc0[15]);
    acc1[12] = mfma16(a3, q0, acc1[12]);
    acc1[13] = mfma16(a3, q1, acc1[13]);
    acc1[14] = mfma16(a3, q2, acc1[14]);
    acc1[15] = mfma16(a3, q3, acc1[15]);
    __syncthreads();
  }
}

// ---------------------------------------------------------------------------
// GEMM1a (qkv cols 0..1151), RoPE + layout fused.
// ---------------------------------------------------------------------------
__global__ __launch_bounds__(256, 2) void gemm1_qkv_kernel(
    const bf16_t* __restrict__ xn, const bf16_t* __restrict__ wfT,
    bf16_t* __restrict__ Q, bf16_t* __restrict__ K, bf16_t* __restrict__ Vt)
{
  __shared__ __align__(16) bf16_t As[128 * 32];
  __shared__ __align__(16) bf16_t B0s[128 * 32];
  __shared__ __align__(16) bf16_t B1s[128 * 32];
  const int m0 = blockIdx.x * 128;
  const int y = blockIdx.y;
  const int t = threadIdx.x;
  const int wave = t >> 6, lane = t & 63;
  const int quad = lane >> 4, ln15 = lane & 15;
  const int wm = wave & 1, wn = wave >> 1;

  const int rb = m0 + wm * 64 + quad * 4;
  const float invf0 = exp2f(-(float)ln15 * (LOG2_10K / 32.0f));
  const float invf1 = exp2f(-(float)(16 + ln15) * (LOG2_10K / 32.0f));

  if (y < 4) {
    const bf16_t* gA  = xn  + (size_t)(m0 + (t >> 2)) * 2048 + ((t & 3) << 3);
    const bf16_t* gB0 = wfT + (size_t)(y * 256 + (t >> 2)) * 2048 + ((t & 3) << 3);
    const bf16_t* gB1 = wfT + (size_t)(y * 256 + 128 + (t >> 2)) * 2048 + ((t & 3) << 3);
    f32x4 acc0[16], acc1[16];
    #pragma unroll
    for (int f = 0; f < 16; ++f) {
      acc0[f] = (f32x4){0.f, 0.f, 0.f, 0.f};
      acc1[f] = (f32x4){0.f, 0.f, 0.f, 0.f};
    }
    gemm_core_dual(gA, gB0, gB1, 2048, 2048, 2048, As, B0s, B1s, acc0, acc1);
    #pragma unroll
    for (int half = 0; half < 2; ++half) {
      const f32x4* acc = half ? acc1 : acc0;
      const int hd = y * 4 + half * 2 + wn;
      #pragma unroll
      for (int i = 0; i < 4; ++i) {
        #pragma unroll
        for (int rr = 0; rr < 4; ++rr) {
          const int row = rb + i * 16 + rr;
          const int b = row >> 11, n = row & 2047;
          const float fn = (float)n;
          float s0, c0, s1, c1;
          __sincosf(fn * invf0, &s0, &c0);
          __sincosf(fn * invf1, &s1, &c1);
          float vals[4];
          #pragma unroll
          for (int j = 0; j < 4; ++j) vals[j] = acc[i * 4 + j][rr];
          #pragma unroll
          for (int j = 0; j < 4; ++j) {
            const float rot = (j < 2) ? -vals[j + 2] : vals[j - 2];
            const float c = (j & 1) ? c1 : c0;
            const float s = (j & 1) ? s1 : s0;
            const float o = (vals[j] * c + rot * s) * 0.125f;
            Q[(((size_t)b * 16 + hd) * 2048 + n) * 64 + j * 16 + ln15] = (bf16_t)o;
          }
        }
      }
    }
  } else {
    f32x4 acc[16];
    #pragma unroll
    for (int f = 0; f < 16; ++f) acc[f] = (f32x4){0.f, 0.f, 0.f, 0.f};
    gemm_core_128x128(xn, 2048, m0, wfT, 2048, 1024, 2048, As, B0s, acc);
    const bool is_k = (wn == 0);
    #pragma unroll
    for (int i = 0; i < 4; ++i) {
      #pragma unroll
      for (int rr = 0; rr < 4; ++rr) {
        const int row = rb + i * 16 + rr;
        const int b = row >> 11, n = row & 2047;
        float vals[4];
        #pragma unroll
        for (int j = 0; j < 4; ++j) vals[j] = acc[i * 4 + j][rr];
        if (is_k) {
          const float fn = (float)n;
          float s0, c0, s1, c1;
          __sincosf(fn * invf0, &s0, &c0);
          __sincosf(fn * invf1, &s1, &c1);
          #pragma unroll
          for (int j = 0; j < 4; ++j) {
            const float rot = (j < 2) ? -vals[j + 2] : vals[j - 2];
            const float c = (j & 1) ? c1 : c0;
            const float s = (j & 1) ? s1 : s0;
            K[((size_t)b * 2048 + n) * 64 + j * 16 + ln15] = (bf16_t)(vals[j] * c + rot * s);
          }
        } else {
          #pragma unroll
          for (int j = 0; j < 4; ++j)
            Vt[((size_t)b * 64 + j * 16 + ln15) * 2048 + n] = (bf16_t)vals[j];
        }
      }
    }
  }
}

// ===========================================================================
// Register-prefetch pipelined cores (R5 schedule, R6 waitcnt intrinsics)
// ===========================================================================

#define FF_STG() {                                                           \
    char* lA_ = lds + sst + w * 1024;                                        \
    gload_lds16(gA, lA_);                                                    \
    gload_lds16(gA + (size_t)128 * 2048, lA_ + 8192);                        \
    char* lB_ = lds + 65536 + sst + w * 1024;                                \
    gload_lds16(gB0, lB_);                                                   \
    gload_lds16(gB1, lB_ + 8192);                                            \
    gA += 32; gB0 += 32; gB1 += 32;                                          \
    sst = (sst + 16384) & 65535; }

#define FF_RD(DA, DB) {                                                      \
    _Pragma("unroll")                                                        \
    for (int mf_ = 0; mf_ < 8; ++mf_)                                        \
      DA[mf_] = *(const bf16x8*)(lds + srd + wm * 8192 + mf_ * 1024 + ro);   \
    _Pragma("unroll")                                                        \
    for (int nf_ = 0; nf_ < 4; ++nf_)                                        \
      DB[nf_] = *(const bf16x8*)(lds + 65536 + srd + wn * 4096 + nf_ * 1024 + ro); \
    srd = (srd + 16384) & 65535;                                             \
    __builtin_amdgcn_sched_barrier(0); }

#define FF_MM(SA, SB) {                                                      \
    __builtin_amdgcn_s_setprio(1);                                           \
    _Pragma("unroll")                                                        \
    for (int mf_ = 0; mf_ < 8; ++mf_) {                                      \
      _Pragma("unroll")                                                      \
      for (int nf_ = 0; nf_ < 4; ++nf_)                                      \
        acc[mf_][nf_] = mfma16(SA[mf_], SB[nf_], acc[mf_][nf_]);             \
    }                                                                        \
    __builtin_amdgcn_s_setprio(0); }

#define FF_SYNC4() { WAITCNT_VM(4); __builtin_amdgcn_s_barrier(); }

// ---------------------------------------------------------------------------
// GEMM1b (ff): BM=256, B = 128 gate + 128 x rows interleaved (16-row), BK=32,
// 512 thr (8 waves 2Mx4N). 4-slot LDS ring (128 KB), reg-prefetch pipeline.
// ---------------------------------------------------------------------------
__global__ __launch_bounds__(512, 2) void gemm1_ff_kernel(
    const bf16_t* __restrict__ xn, const bf16_t* __restrict__ wfT,
    bf16_t* __restrict__ A2)
{
  __shared__ __align__(16) char lds[131072];
  const int m0 = blockIdx.x * 256;
  const int c0 = blockIdx.y * 128;
  const int t = threadIdx.x;
  const int w = t >> 6, lane = t & 63;
  const int quad = lane >> 4, ln15 = lane & 15;
  const int wm = w & 1, wn = w >> 1;          // 2 x 4 wave grid

  const int p  = w * 64 + lane;
  const int r  = p >> 2;
  const int cl = (p & 3) ^ ((r >> 1) & 3);
  const bf16_t* gA = xn + (size_t)(m0 + r) * 2048 + cl * 8;
  const int r2 = r + 128;
  const int cm0 = c0 + ((r  >> 5) << 4) + (r  & 15);
  const int cm1 = c0 + ((r2 >> 5) << 4) + (r2 & 15);
  const int wr0 = ((r  >> 4) & 1) ? (1152 + cm0) : (9344 + cm0);
  const int wr1 = ((r2 >> 4) & 1) ? (1152 + cm1) : (9344 + cm1);
  const bf16_t* gB0 = wfT + (size_t)wr0 * 2048 + cl * 8;
  const bf16_t* gB1 = wfT + (size_t)wr1 * 2048 + cl * 8;

  const int ro = ln15 * 64 + ((quad ^ ((ln15 >> 1) & 3)) * 16);

  f32x4 acc[8][4];
  #pragma unroll
  for (int mf = 0; mf < 8; ++mf)
    #pragma unroll
    for (int nf = 0; nf < 4; ++nf)
      acc[mf][nf] = (f32x4){0.f, 0.f, 0.f, 0.f};

  int sst = 0, srd = 0;
  // prologue: stage tiles 0,1,2 (12 loads)
  #pragma unroll
  for (int pt = 0; pt < 3; ++pt) FF_STG();
  // tiles 0,1 complete (oldest 8 of 12 retired); tile 2 still in flight
  FF_SYNC4();

  bf16x8 fA[8], fB[4], nA[8], nB[4];
  FF_RD(fA, fB);                         // frags(0); srd -> 16384

  // main loop: tt = 0..60 (uniform). invariant at top: only tile tt+2 in flight
  for (int i = 0; i < 30; ++i) {
    FF_STG(); FF_RD(nA, nB); FF_MM(fA, fB); FF_SYNC4();   // tt even
    FF_STG(); FF_RD(fA, fB); FF_MM(nA, nB); FF_SYNC4();   // tt odd
  }
  FF_STG(); FF_RD(nA, nB); FF_MM(fA, fB); FF_SYNC4();     // tt=60 (stages 63)
  // tail: tiles 61..63
  FF_RD(fA, fB); FF_MM(nA, nB);                           // tt=61, reads 62
  WAITCNT_VM(0);
  __builtin_amdgcn_s_barrier();
  FF_RD(nA, nB); FF_MM(fA, fB);                           // tt=62, reads 63
  FF_MM(nA, nB);                                          // tt=63

  // epilogue: silu(gate)*x -> A2 cols [0,8192)
  const int row0 = m0 + wm * 128 + quad * 4;
  const int col0 = c0 + wn * 32 + ln15;
  #pragma unroll
  for (int mf = 0; mf < 8; ++mf)
    #pragma unroll
    for (int rr = 0; rr < 4; ++rr) {
      bf16_t* dst = A2 + (size_t)(row0 + mf * 16 + rr) * 9216 + col0;
      #pragma unroll
      for (int j = 0; j < 2; ++j) {
        const float g  = acc[mf][2 * j][rr];
        const float xv = acc[mf][2 * j + 1][rr];
        dst[j * 16] = (bf16_t)(xv * (g / (1.f + exp2f(-g * LOG2E))));
      }
    }
}

#define G2_STG() {                                                           \
    char* lA_ = lds + sstA + w * 1024;                                       \
    gload_lds16(gA, lA_);                                                    \
    gload_lds16(gA + (size_t)128 * 9216, lA_ + 8192);                        \
    gload_lds16(gB, lds + 65536 + sstB + w * 1024);                          \
    gA += 32; gB += 32;                                                      \
    sstA = (sstA + 16384) & 65535;                                           \
    sstB = (sstB + 8192) & 32767; }

#define G2_RD(DA, DB) {                                                      \
    _Pragma("unroll")                                                        \
    for (int mf_ = 0; mf_ < 4; ++mf_)                                        \
      DA[mf_] = *(const bf16x8*)(lds + srdA + wm * 4096 + mf_ * 1024 + ro);  \
    _Pragma("unroll")                                                        \
    for (int nf_ = 0; nf_ < 4; ++nf_)                                        \
      DB[nf_] = *(const bf16x8*)(lds + 65536 + srdB + wn * 4096 + nf_ * 1024 + ro); \
    srdA = (srdA + 16384) & 65535;                                           \
    srdB = (srdB + 8192) & 32767;                                            \
    __builtin_amdgcn_sched_barrier(0); }

#define G2_MM(SA, SB) {                                                      \
    __builtin_amdgcn_s_setprio(1);                                           \
    _Pragma("unroll")                                                        \
    for (int mf_ = 0; mf_ < 4; ++mf_) {                                      \
      _Pragma("unroll")                                                      \
      for (int nf_ = 0; nf_ < 4; ++nf_)                                      \
        acc[mf_][nf_] = mfma16(SA[mf_], SB[nf_], acc[mf_][nf_]);             \
    }                                                                        \
    __builtin_amdgcn_s_setprio(0); }

#define G2_SYNC3() { WAITCNT_VM(3); __builtin_amdgcn_s_barrier(); }

// ---------------------------------------------------------------------------
// GEMM2: out = A2(4096x9216) @ w2T^T. BM=256/BN=128, BK=32, 512 thr (4Mx2N).
// Grid 16x16=256 blocks, no split-K, direct f32 stores. 4-slot ring (96 KB),
// reg-prefetch pipeline.
// ---------------------------------------------------------------------------
__global__ __launch_bounds__(512, 2) void gemm2_kernel(
    const bf16_t* __restrict__ A2, const bf16_t* __restrict__ w2T,
    float* __restrict__ out)
{
  __shared__ __align__(16) char lds[98304];
  const int m0 = blockIdx.x * 256;
  const int n0 = blockIdx.y * 128;
  const int t = threadIdx.x;
  const int w = t >> 6, lane = t & 63;
  const int quad = lane >> 4, ln15 = lane & 15;
  const int wm = w & 3, wn = w >> 2;          // 4 x 2 wave grid

  const int p  = w * 64 + lane;
  const int r  = p >> 2;
  const int cl = (p & 3) ^ ((r >> 1) & 3);
  const bf16_t* gA = A2  + (size_t)(m0 + r) * 9216 + cl * 8;
  const bf16_t* gB = w2T + (size_t)(n0 + r) * 9216 + cl * 8;

  const int ro = ln15 * 64 + ((quad ^ ((ln15 >> 1) & 3)) * 16);

  f32x4 acc[4][4];
  #pragma unroll
  for (int mf = 0; mf < 4; ++mf)
    #pragma unroll
    for (int nf = 0; nf < 4; ++nf)
      acc[mf][nf] = (f32x4){0.f, 0.f, 0.f, 0.f};

  int sstA = 0, sstB = 0, srdA = 0, srdB = 0;
  #pragma unroll
  for (int pt = 0; pt < 3; ++pt) G2_STG();
  // 9 loads out; wait -> 3 remain: tiles 0,1 complete
  G2_SYNC3();

  bf16x8 fA[4], fB[4], nA[4], nB[4];
  G2_RD(fA, fB);                          // frags(0)

  // main loop: tt = 0..284 (uniform)
  for (int i = 0; i < 142; ++i) {
    G2_STG(); G2_RD(nA, nB); G2_MM(fA, fB); G2_SYNC3();
    G2_STG(); G2_RD(fA, fB); G2_MM(nA, nB); G2_SYNC3();
  }
  G2_STG(); G2_RD(nA, nB); G2_MM(fA, fB); G2_SYNC3();     // tt=284 (stages 287)
  // tail: 285..287
  G2_RD(fA, fB); G2_MM(nA, nB);                           // tt=285, reads 286
  WAITCNT_VM(0);
  __builtin_amdgcn_s_barrier();
  G2_RD(nA, nB); G2_MM(fA, fB);                           // tt=286, reads 287
  G2_MM(nA, nB);                                          // tt=287

  const int row0 = m0 + wm * 64 + quad * 4;
  const int col0 = n0 + wn * 64 + ln15;
  #pragma unroll
  for (int mf = 0; mf < 4; ++mf)
    #pragma unroll
    for (int rr = 0; rr < 4; ++rr) {
      float* dst = out + (size_t)(row0 + mf * 16 + rr) * 2048 + col0;
      #pragma unroll
      for (int nf = 0; nf < 4; ++nf)
        dst[nf * 16] = acc[mf][nf][rr];
    }
}

// ---------------------------------------------------------------------------
// Causal MQA flash attention -> A2[:, 8192 + h*64 + d]. Paired Q-tiles
// (qt = p and 31-p), grid (16,32), 512 blocks, LDS 32 KB.
// R15: s_setprio(1)/(0) around the QK^T and PV MFMA clusters (m191 regime:
// 2 independent blocks/CU at different phases).
// ---------------------------------------------------------------------------
__global__ __launch_bounds__(256, 2) void attn_kernel(
    const bf16_t* __restrict__ Q, const bf16_t* __restrict__ Kg_,
    const bf16_t* __restrict__ Vt, bf16_t* __restrict__ A2)
{
  __shared__ __align__(16) bf16_t Qs[64 * 64];
  __shared__ __align__(16) bf16_t Ks[64 * 64];
  __shared__ __align__(16) bf16_t Vs[64 * 64];
  __shared__ __align__(16) bf16_t Ps[64 * 64];
  const int pidx = blockIdx.x, bh = blockIdx.y;
  const int b = bh >> 4, h = bh & 15;
  const int t = threadIdx.x;
  const int wave = t >> 6, lane = t & 63;
  const int quad = lane >> 4, ln15 = lane & 15;

  const bf16_t* Kg = Kg_ + (size_t)b * 2048 * 64;
  const bf16_t* Vg = Vt + (size_t)b * 64 * 2048;

  for (int hlf = 0; hlf < 2; ++hlf) {
    const int qt = hlf ? (31 - pidx) : pidx;
    const int qm0 = qt * 64;
    const bf16_t* Qg = Q + ((size_t)bh * 2048 + qm0) * 64;

    { // stage Q tile (8 KB, 2 rounds)
      const bf16_t* g = Qg + (size_t)(t >> 3) * 64 + ((t & 7) << 3);
      char* l = (char*)Qs + wave * 1024;
      gload_lds16(g,           l);
      gload_lds16(g + 32 * 64, l + 4096);
    }

    float mstate[4], lstate[4];
    f32x4 o_acc[4];
    #pragma unroll
    for (int rr = 0; rr < 4; ++rr) { mstate[rr] = -1e30f; lstate[rr] = 0.f; }
    #pragma unroll
    for (int jd = 0; jd < 4; ++jd) o_acc[jd] = (f32x4){0.f, 0.f, 0.f, 0.f};

    const int njt = qt + 1;
    for (int jt = 0; jt < njt; ++jt) {
      { // stage K, V tiles (8 KB each)
        const bf16_t* kg = Kg + (size_t)(jt * 64 + (t >> 3)) * 64 + ((t & 7) << 3);
        char* lk = (char*)Ks + wave * 1024;
        gload_lds16(kg,           lk);
        gload_lds16(kg + 32 * 64, lk + 4096);
        const bf16_t* vg = Vg + (size_t)(t >> 3) * 2048 + jt * 64 + ((t & 7) << 3);
        char* lv = (char*)Vs + wave * 1024;
        gload_lds16(vg,                   lv);
        gload_lds16(vg + (size_t)32*2048, lv + 4096);
      }
      __syncthreads();

      f32x4 sA[4];
      #pragma unroll
      for (int j = 0; j < 4; ++j) sA[j] = (f32x4){0.f, 0.f, 0.f, 0.f};
      __builtin_amdgcn_s_setprio(1);
      #pragma unroll
      for (int ks = 0; ks < 2; ++ks) {
        bf16x8 aq = *(const bf16x8*)(Qs + (wave * 16 + ln15) * 64 + ks * 32 + quad * 8);
        #pragma unroll
        for (int j = 0; j < 4; ++j) {
          bf16x8 bk = *(const bf16x8*)(Ks + (j * 16 + ln15) * 64 + ks * 32 + quad * 8);
          sA[j] = mfma16(aq, bk, sA[j]);
        }
      }
      __builtin_amdgcn_s_setprio(0);

      const bool needmask = (jt * 64 + 63 > qm0 + wave * 16);
      const int row0 = qm0 + wave * 16 + quad * 4;
      float alpha[4];
      #pragma unroll
      for (int rr = 0; rr < 4; ++rr) {
        const int rowg = row0 + rr;
        if (needmask) {
          #pragma unroll
          for (int j = 0; j < 4; ++j) {
            const int colg = jt * 64 + j * 16 + ln15;
            if (colg > rowg) sA[j][rr] = -1e30f;
          }
        }
        float mx = fmaxf(fmaxf(sA[0][rr], sA[1][rr]),
                         fmaxf(sA[2][rr], sA[3][rr]));
        mx = fmaxf(mx, __shfl_xor(mx, 1));
        mx = fmaxf(mx, __shfl_xor(mx, 2));
        mx = fmaxf(mx, __shfl_xor(mx, 4));
        mx = fmaxf(mx, __shfl_xor(mx, 8));
        const float mold = mstate[rr];
        const float mnew = fmaxf(mold, mx);
        const float al = exp2f((mold - mnew) * LOG2E);
        float rsum = 0.f;
        #pragma unroll
        for (int j = 0; j < 4; ++j) {
          const float p = exp2f((sA[j][rr] - mnew) * LOG2E);
          sA[j][rr] = p;
          rsum += p;
        }
        rsum += __shfl_xor(rsum, 1);
        rsum += __shfl_xor(rsum, 2);
        rsum += __shfl_xor(rsum, 4);
        rsum += __shfl_xor(rsum, 8);
        lstate[rr] = lstate[rr] * al + rsum;
        mstate[rr] = mnew;
        alpha[rr] = al;
      }
      #pragma unroll
      for (int jd = 0; jd < 4; ++jd)
        #pragma unroll
        for (int rr = 0; rr < 4; ++rr)
          o_acc[jd][rr] *= alpha[rr];
      #pragma unroll
      for (int j = 0; j < 4; ++j)
        #pragma unroll
        for (int rr = 0; rr < 4; ++rr)
          Ps[wave * 1024 + (quad * 4 + rr) * 64 + j * 16 + ln15] = (bf16_t)sA[j][rr];

      __builtin_amdgcn_s_setprio(1);
      #pragma unroll
      for (int ks = 0; ks < 2; ++ks) {
        bf16x8 ap = *(const bf16x8*)(Ps + wave * 1024 + ln15 * 64 + ks * 32 + quad * 8);
        #pragma unroll
        for (int jd = 0; jd < 4; ++jd) {
          bf16x8 bv = *(const bf16x8*)(Vs + (jd * 16 + ln15) * 64 + ks * 32 + quad * 8);
          o_acc[jd] = mfma16(ap, bv, o_acc[jd]);
        }
      }
      __builtin_amdgcn_s_setprio(0);
      __syncthreads();
    }

    const int row0 = qm0 + wave * 16 + quad * 4;
    #pragma unroll
    for (int rr = 0; rr < 4; ++rr) {
      const float inv = 1.f / lstate[rr];
      bf16_t* dst = A2 + ((size_t)b * 2048 + row0 + rr) * 9216 + 8192 + h * 64 + ln15;
      #pragma unroll
      for (int jd = 0; jd < 4; ++jd)
        dst[jd * 16] = (bf16_t)(o_acc[jd][rr] * inv);
    }
  }
}

// ---------------------------------------------------------------------------
extern "C" void kernel_launch(void* const* d_in, const int* in_sizes, int n_in,
                              void* d_out, int out_size, void* d_ws, size_t ws_size,
                              hipStream_t stream)
{
  const float* x      = (const float*)d_in[0];
  const float* gamma  = (const float*)d_in[1];
  const float* wfused = (const float*)d_in[2];
  const float* watt   = (const float*)d_in[3];
  const float* wff    = (const float*)d_in[4];
  const float* qa     = (const float*)d_in[5];
  const float* qb     = (const float*)d_in[6];
  const float* ka     = (const float*)d_in[7];
  const float* kb     = (const float*)d_in[8];
  const float* va     = (const float*)d_in[9];
  const float* vb     = (const float*)d_in[10];
  const float* oa     = (const float*)d_in[11];
  const float* ob     = (const float*)d_in[12];
  float* out = (float*)d_out;

  char* ws = (char*)d_ws;
  bf16_t* xn  = (bf16_t*)(ws);                    // 16,777,216
  bf16_t* wfT = (bf16_t*)(ws + 16777216);         // 71,827,456
  bf16_t* w2T = (bf16_t*)(ws + 88604672);         // 37,748,736
  bf16_t* A2  = (bf16_t*)(ws + 126353408);        // 75,497,472
  bf16_t* Qr  = (bf16_t*)(ws + 201850880);        //  8,388,608
  bf16_t* Kr  = (bf16_t*)(ws + 210239488);        //    524,288
  bf16_t* Vtr = (bf16_t*)(ws + 210763776);        //    524,288

  ln_kernel<<<dim3(4096), dim3(256), 0, stream>>>(x, gamma, xn);
  transpose_wf_kernel<<<dim3(274, 32), dim3(256), 0, stream>>>(
      wfused, qa, qb, ka, kb, va, vb, wfT);
  transpose_w2_kernel<<<dim3(32, 144), dim3(256), 0, stream>>>(
      wff, watt, oa, ob, w2T);
  gemm1_qkv_kernel<<<dim3(32, 5), dim3(256), 0, stream>>>(xn, wfT, Qr, Kr, Vtr);
  gemm1_ff_kernel<<<dim3(16, 64), dim3(512), 0, stream>>>(xn, wfT, A2);
  attn_kernel<<<dim3(16, 32), dim3(256), 0, stream>>>(Qr, Kr, Vtr, A2);
  gemm2_kernel<<<dim3(16, 16), dim3(512), 0, stream>>>(A2, w2T, out);
}

// Round 13
// 869.422 us; speedup vs baseline: 1.0794x; 1.0019x over previous
//
#include <hip/hip_runtime.h>
#include <cstdint>

// ============================================================================
// ParallelTransformerBlock (PaLM-style parallel attn+FF, MQA, RoPE, LoRA)
// B=2, N=2048, DIM=2048, HEADS=16, DIM_HEAD=64 (MQA), FF_INNER=8192, R=8.
//
// R16 = R15 (measured 871.1 us, session best; attn setprio confirmed -7) plus
// ONE change: attn Q-HOIST — Q fragments are jt-invariant, so load them into
// registers once per half (after an explicit vmcnt(0)+barrier to make the
// cross-wave Q staging visible) instead of 2 ds_read_b128 per K-tile on the
// post-barrier critical path (m164-m191 ladder technique, paired w/ setprio).
// Everything else byte-identical to R15.
// ============================================================================

typedef __bf16 bf16_t;
typedef __bf16 bf16x8 __attribute__((ext_vector_type(8)));
typedef float f32x4 __attribute__((ext_vector_type(4)));

#define LOG2E 1.44269504088896340736f
#define LOG2_10K 13.287712379549449f   // log2(10000)

// s_waitcnt simm16 (gfx9-class): vmcnt[3:0]=bits3:0, expcnt=bits6:4,
// lgkmcnt=bits11:8, vmcnt[5:4]=bits15:14.
#define WAITCNT_VM(N) __builtin_amdgcn_s_waitcnt(0x0F70 | (N))   // vmcnt(N) only

__device__ __forceinline__ void gload_lds16(const void* g, void* l) {
  __builtin_amdgcn_global_load_lds(
      (__attribute__((address_space(1))) void*)(uintptr_t)g,
      (__attribute__((address_space(3))) void*)(uint32_t)(uintptr_t)l,
      16, 0, 0);
}

__device__ __forceinline__ f32x4 mfma16(bf16x8 a, bf16x8 b, f32x4 c) {
  return __builtin_amdgcn_mfma_f32_16x16x32_bf16(a, b, c, 0, 0, 0);
}

// ---------------------------------------------------------------------------
// LayerNorm: one block per token row (4096 rows x 2048)
// ---------------------------------------------------------------------------
__global__ __launch_bounds__(256) void ln_kernel(
    const float* __restrict__ x, const float* __restrict__ gamma,
    bf16_t* __restrict__ xn)
{
  const int row = blockIdx.x;
  const int t = threadIdx.x;
  const float4* xr = (const float4*)(x + (size_t)row * 2048);
  float4 a = xr[t * 2];
  float4 b = xr[t * 2 + 1];
  float s  = a.x + a.y + a.z + a.w + b.x + b.y + b.z + b.w;
  float ss = a.x*a.x + a.y*a.y + a.z*a.z + a.w*a.w
           + b.x*b.x + b.y*b.y + b.z*b.z + b.w*b.w;
  #pragma unroll
  for (int m = 1; m < 64; m <<= 1) {
    s  += __shfl_xor(s, m);
    ss += __shfl_xor(ss, m);
  }
  __shared__ float red[8];
  const int wave = t >> 6, lane = t & 63;
  if (lane == 0) { red[wave] = s; red[4 + wave] = ss; }
  __syncthreads();
  const float stot  = red[0] + red[1] + red[2] + red[3];
  const float sstot = red[4] + red[5] + red[6] + red[7];
  const float mu  = stot * (1.f / 2048.f);
  const float var = sstot * (1.f / 2048.f) - mu * mu;
  const float rs  = rsqrtf(var + 1e-5f);
  float v[8] = {a.x, a.y, a.z, a.w, b.x, b.y, b.z, b.w};
  bf16x8 o;
  #pragma unroll
  for (int e = 0; e < 8; ++e)
    o[e] = (bf16_t)((v[e] - mu) * rs * gamma[t * 8 + e]);
  *(bf16x8*)(xn + (size_t)row * 2048 + t * 8) = o;
}

// ---------------------------------------------------------------------------
// Transpose+convert w_fused (2048 x 17536 f32) -> wfT (17536 x 2048 bf16),
// folding lora_q/k/v into cols [0,1152). 64x64 tiles, LDS pad +1.
// ---------------------------------------------------------------------------
__global__ __launch_bounds__(256) void transpose_wf_kernel(
    const float* __restrict__ w,
    const float* __restrict__ qa, const float* __restrict__ qb,
    const float* __restrict__ ka, const float* __restrict__ kb,
    const float* __restrict__ va, const float* __restrict__ vb,
    bf16_t* __restrict__ wfT)
{
  __shared__ float tile[64][65];
  const int t  = threadIdx.x;
  const int n0 = blockIdx.x * 64;
  const int k0 = blockIdx.y * 64;
  #pragma unroll
  for (int it = 0; it < 4; ++it) {
    const int kr = (t >> 4) + it * 16;
    const float4 vv = *(const float4*)(w + (size_t)(k0 + kr) * 17536 + n0 + (t & 15) * 4);
    tile[kr][(t & 15) * 4 + 0] = vv.x;
    tile[kr][(t & 15) * 4 + 1] = vv.y;
    tile[kr][(t & 15) * 4 + 2] = vv.z;
    tile[kr][(t & 15) * 4 + 3] = vv.w;
  }
  __syncthreads();
  const float* la = nullptr; const float* lb = nullptr;
  int nbo = 0, ldlb = 0;
  if (n0 < 1024)      { la = qa; lb = qb; nbo = n0;        ldlb = 1024; }
  else if (n0 < 1088) { la = ka; lb = kb; nbo = n0 - 1024; ldlb = 64;   }
  else if (n0 < 1152) { la = va; lb = vb; nbo = n0 - 1088; ldlb = 64;   }
  #pragma unroll
  for (int it = 0; it < 2; ++it) {
    const int nl = (t >> 3) + it * 32;
    const int kl = (t & 7) * 8;
    float vals[8];
    #pragma unroll
    for (int e = 0; e < 8; ++e) vals[e] = tile[kl + e][nl];
    if (la) {
      float bc[8];
      #pragma unroll
      for (int r = 0; r < 8; ++r) bc[r] = lb[r * ldlb + nbo + nl];
      #pragma unroll
      for (int e = 0; e < 8; ++e) {
        const float* ar = la + (size_t)(k0 + kl + e) * 8;
        float d = 0.f;
        #pragma unroll
        for (int r = 0; r < 8; ++r) d += ar[r] * bc[r];
        vals[e] += d;
      }
    }
    bf16x8 o;
    #pragma unroll
    for (int e = 0; e < 8; ++e) o[e] = (bf16_t)vals[e];
    *(bf16x8*)(wfT + (size_t)(n0 + nl) * 2048 + k0 + kl) = o;
  }
}

// ---------------------------------------------------------------------------
// Build w2T (2048 x 9216 bf16): cols [0,8192) = w_ff_out^T,
// cols [8192,9216) = (w_attn_out + lora_o_a@lora_o_b)^T.
// ---------------------------------------------------------------------------
__global__ __launch_bounds__(256) void transpose_w2_kernel(
    const float* __restrict__ wff,   // 8192 x 2048
    const float* __restrict__ watt,  // 1024 x 2048
    const float* __restrict__ oa, const float* __restrict__ ob,
    bf16_t* __restrict__ w2T)
{
  __shared__ float tile[64][65];
  const int t  = threadIdx.x;
  const int n0 = blockIdx.x * 64;
  const int k0 = blockIdx.y * 64;          // 0..9152
  const bool isatt = (k0 >= 8192);
  const float* src = isatt ? (watt + (size_t)(k0 - 8192) * 2048)
                           : (wff + (size_t)k0 * 2048);
  #pragma unroll
  for (int it = 0; it < 4; ++it) {
    const int kr = (t >> 4) + it * 16;
    const float4 vv = *(const float4*)(src + (size_t)kr * 2048 + n0 + (t & 15) * 4);
    tile[kr][(t & 15) * 4 + 0] = vv.x;
    tile[kr][(t & 15) * 4 + 1] = vv.y;
    tile[kr][(t & 15) * 4 + 2] = vv.z;
    tile[kr][(t & 15) * 4 + 3] = vv.w;
  }
  __syncthreads();
  #pragma unroll
  for (int it = 0; it < 2; ++it) {
    const int nl = (t >> 3) + it * 32;
    const int kl = (t & 7) * 8;
    float vals[8];
    #pragma unroll
    for (int e = 0; e < 8; ++e) vals[e] = tile[kl + e][nl];
    if (isatt) {
      float bc[8];
      #pragma unroll
      for (int r = 0; r < 8; ++r) bc[r] = ob[r * 2048 + n0 + nl];
      #pragma unroll
      for (int e = 0; e < 8; ++e) {
        const float* ar = oa + (size_t)(k0 - 8192 + kl + e) * 8;
        float d = 0.f;
        #pragma unroll
        for (int r = 0; r < 8; ++r) d += ar[r] * bc[r];
        vals[e] += d;
      }
    }
    bf16x8 o;
    #pragma unroll
    for (int e = 0; e < 8; ++e) o[e] = (bf16_t)vals[e];
    *(bf16x8*)(w2T + (size_t)(n0 + nl) * 9216 + k0 + kl) = o;
  }
}

// ---------------------------------------------------------------------------
// Single-B GEMM core: C[128x128] += A * BT^T (16 MFMA/barrier).  (qkv only)
// ---------------------------------------------------------------------------
__device__ __forceinline__ void gemm_core_128x128(
    const bf16_t* __restrict__ A, int ldA, int m0,
    const bf16_t* __restrict__ BT, int ldB, int n0,
    int K, bf16_t* As, bf16_t* Bs, f32x4* acc)
{
  const int t = threadIdx.x;
  const int wave = t >> 6;
  const int lane = t & 63;
  const int quad = lane >> 4;
  const int ln15 = lane & 15;
  const int wm = wave & 1, wn = wave >> 1;

  const bf16_t* gA = A + (size_t)(m0 + (t >> 2)) * ldA + ((t & 3) << 3);
  const bf16_t* gB = BT + (size_t)(n0 + (t >> 2)) * ldB + ((t & 3) << 3);
  char* lA = (char*)As + wave * 1024;
  char* lB = (char*)Bs + wave * 1024;
  const size_t sA64 = (size_t)64 * ldA;
  const size_t sB64 = (size_t)64 * ldB;
  const int aoff = (wm * 64 + ln15) * 32 + quad * 8;
  const int boff = (wn * 64 + ln15) * 32 + quad * 8;

  for (int kt = 0; kt < K; kt += 32) {
    gload_lds16(gA,        lA);
    gload_lds16(gA + sA64, lA + 4096);
    gload_lds16(gB,        lB);
    gload_lds16(gB + sB64, lB + 4096);
    gA += 32;
    gB += 32;
    __syncthreads();
    bf16x8 a0 = *(const bf16x8*)(As + aoff);
    bf16x8 a1 = *(const bf16x8*)(As + aoff + 512);
    bf16x8 a2 = *(const bf16x8*)(As + aoff + 1024);
    bf16x8 a3 = *(const bf16x8*)(As + aoff + 1536);
    bf16x8 b0 = *(const bf16x8*)(Bs + boff);
    bf16x8 b1 = *(const bf16x8*)(Bs + boff + 512);
    bf16x8 b2 = *(const bf16x8*)(Bs + boff + 1024);
    bf16x8 b3 = *(const bf16x8*)(Bs + boff + 1536);
    acc[0]  = mfma16(a0, b0, acc[0]);
    acc[1]  = mfma16(a0, b1, acc[1]);
    acc[2]  = mfma16(a0, b2, acc[2]);
    acc[3]  = mfma16(a0, b3, acc[3]);
    acc[4]  = mfma16(a1, b0, acc[4]);
    acc[5]  = mfma16(a1, b1, acc[5]);
    acc[6]  = mfma16(a1, b2, acc[6]);
    acc[7]  = mfma16(a1, b3, acc[7]);
    acc[8]  = mfma16(a2, b0, acc[8]);
    acc[9]  = mfma16(a2, b1, acc[9]);
    acc[10] = mfma16(a2, b2, acc[10]);
    acc[11] = mfma16(a2, b3, acc[11]);
    acc[12] = mfma16(a3, b0, acc[12]);
    acc[13] = mfma16(a3, b1, acc[13]);
    acc[14] = mfma16(a3, b2, acc[14]);
    acc[15] = mfma16(a3, b3, acc[15]);
    __syncthreads();
  }
}

// ---------------------------------------------------------------------------
// Dual-B GEMM core: one A tile, two B tiles, 32 MFMA/barrier.  (qkv only)
// ---------------------------------------------------------------------------
__device__ __forceinline__ void gemm_core_dual(
    const bf16_t* gA, const bf16_t* gB0, const bf16_t* gB1,
    int ldA, int ldB, int K,
    bf16_t* As, bf16_t* B0s, bf16_t* B1s,
    f32x4* acc0, f32x4* acc1)
{
  const int t = threadIdx.x;
  const int wave = t >> 6;
  const int lane = t & 63;
  const int quad = lane >> 4;
  const int ln15 = lane & 15;
  const int wm = wave & 1, wn = wave >> 1;

  char* lA = (char*)As + wave * 1024;
  char* l0 = (char*)B0s + wave * 1024;
  char* l1 = (char*)B1s + wave * 1024;
  const size_t sA64 = (size_t)64 * ldA;
  const size_t sB64 = (size_t)64 * ldB;
  const int aoff = (wm * 64 + ln15) * 32 + quad * 8;
  const int boff = (wn * 64 + ln15) * 32 + quad * 8;

  for (int kt = 0; kt < K; kt += 32) {
    gload_lds16(gA,         lA);
    gload_lds16(gA + sA64,  lA + 4096);
    gload_lds16(gB0,        l0);
    gload_lds16(gB0 + sB64, l0 + 4096);
    gload_lds16(gB1,        l1);
    gload_lds16(gB1 + sB64, l1 + 4096);
    gA += 32; gB0 += 32; gB1 += 32;
    __syncthreads();
    bf16x8 a0 = *(const bf16x8*)(As + aoff);
    bf16x8 a1 = *(const bf16x8*)(As + aoff + 512);
    bf16x8 a2 = *(const bf16x8*)(As + aoff + 1024);
    bf16x8 a3 = *(const bf16x8*)(As + aoff + 1536);
    bf16x8 p0 = *(const bf16x8*)(B0s + boff);
    bf16x8 p1 = *(const bf16x8*)(B0s + boff + 512);
    bf16x8 p2 = *(const bf16x8*)(B0s + boff + 1024);
    bf16x8 p3 = *(const bf16x8*)(B0s + boff + 1536);
    bf16x8 q0 = *(const bf16x8*)(B1s + boff);
    bf16x8 q1 = *(const bf16x8*)(B1s + boff + 512);
    bf16x8 q2 = *(const bf16x8*)(B1s + boff + 1024);
    bf16x8 q3 = *(const bf16x8*)(B1s + boff + 1536);
    acc0[0]  = mfma16(a0, p0, acc0[0]);
    acc0[1]  = mfma16(a0, p1, acc0[1]);
    acc0[2]  = mfma16(a0, p2, acc0[2]);
    acc0[3]  = mfma16(a0, p3, acc0[3]);
    acc1[0]  = mfma16(a0, q0, acc1[0]);
    acc1[1]  = mfma16(a0, q1, acc1[1]);
    acc1[2]  = mfma16(a0, q2, acc1[2]);
    acc1[3]  = mfma16(a0, q3, acc1[3]);
    acc0[4]  = mfma16(a1, p0, acc0[4]);
    acc0[5]  = mfma16(a1, p1, acc0[5]);
    acc0[6]  = mfma16(a1, p2, acc0[6]);
    acc0[7]  = mfma16(a1, p3, acc0[7]);
    acc1[4]  = mfma16(a1, q0, acc1[4]);
    acc1[5]  = mfma16(a1, q1, acc1[5]);
    acc1[6]  = mfma16(a1, q2, acc1[6]);
    acc1[7]  = mfma16(a1, q3, acc1[7]);
    acc0[8]  = mfma16(a2, p0, acc0[8]);
    acc0[9]  = mfma16(a2, p1, acc0[9]);
    acc0[10] = mfma16(a2, p2, acc0[10]);
    acc0[11] = mfma16(a2, p3, acc0[11]);
    acc1[8]  = mfma16(a2, q0, acc1[8]);
    acc1[9]  = mfma16(a2, q1, acc1[9]);
    acc1[10] = mfma16(a2, q2, acc1[10]);
    acc1[11] = mfma16(a2, q3, acc1[11]);
    acc0[12] = mfma16(a3, p0, acc0[12]);
    acc0[13] = mfma16(a3, p1, acc0[13]);
    acc0[14] = mfma16(a3, p2, acc0[14]);
    acc0[15] = mfma16(a3, p3, acc0[15]);
    acc1[12] = mfma16(a3, q0, acc1[12]);
    acc1[13] = mfma16(a3, q1, acc1[13]);
    acc1[14] = mfma16(a3, q2, acc1[14]);
    acc1[15] = mfma16(a3, q3, acc1[15]);
    __syncthreads();
  }
}

// ---------------------------------------------------------------------------
// GEMM1a (qkv cols 0..1151), RoPE + layout fused.
// ---------------------------------------------------------------------------
__global__ __launch_bounds__(256, 2) void gemm1_qkv_kernel(
    const bf16_t* __restrict__ xn, const bf16_t* __restrict__ wfT,
    bf16_t* __restrict__ Q, bf16_t* __restrict__ K, bf16_t* __restrict__ Vt)
{
  __shared__ __align__(16) bf16_t As[128 * 32];
  __shared__ __align__(16) bf16_t B0s[128 * 32];
  __shared__ __align__(16) bf16_t B1s[128 * 32];
  const int m0 = blockIdx.x * 128;
  const int y = blockIdx.y;
  const int t = threadIdx.x;
  const int wave = t >> 6, lane = t & 63;
  const int quad = lane >> 4, ln15 = lane & 15;
  const int wm = wave & 1, wn = wave >> 1;

  const int rb = m0 + wm * 64 + quad * 4;
  const float invf0 = exp2f(-(float)ln15 * (LOG2_10K / 32.0f));
  const float invf1 = exp2f(-(float)(16 + ln15) * (LOG2_10K / 32.0f));

  if (y < 4) {
    const bf16_t* gA  = xn  + (size_t)(m0 + (t >> 2)) * 2048 + ((t & 3) << 3);
    const bf16_t* gB0 = wfT + (size_t)(y * 256 + (t >> 2)) * 2048 + ((t & 3) << 3);
    const bf16_t* gB1 = wfT + (size_t)(y * 256 + 128 + (t >> 2)) * 2048 + ((t & 3) << 3);
    f32x4 acc0[16], acc1[16];
    #pragma unroll
    for (int f = 0; f < 16; ++f) {
      acc0[f] = (f32x4){0.f, 0.f, 0.f, 0.f};
      acc1[f] = (f32x4){0.f, 0.f, 0.f, 0.f};
    }
    gemm_core_dual(gA, gB0, gB1, 2048, 2048, 2048, As, B0s, B1s, acc0, acc1);
    #pragma unroll
    for (int half = 0; half < 2; ++half) {
      const f32x4* acc = half ? acc1 : acc0;
      const int hd = y * 4 + half * 2 + wn;
      #pragma unroll
      for (int i = 0; i < 4; ++i) {
        #pragma unroll
        for (int rr = 0; rr < 4; ++rr) {
          const int row = rb + i * 16 + rr;
          const int b = row >> 11, n = row & 2047;
          const float fn = (float)n;
          float s0, c0, s1, c1;
          __sincosf(fn * invf0, &s0, &c0);
          __sincosf(fn * invf1, &s1, &c1);
          float vals[4];
          #pragma unroll
          for (int j = 0; j < 4; ++j) vals[j] = acc[i * 4 + j][rr];
          #pragma unroll
          for (int j = 0; j < 4; ++j) {
            const float rot = (j < 2) ? -vals[j + 2] : vals[j - 2];
            const float c = (j & 1) ? c1 : c0;
            const float s = (j & 1) ? s1 : s0;
            const float o = (vals[j] * c + rot * s) * 0.125f;
            Q[(((size_t)b * 16 + hd) * 2048 + n) * 64 + j * 16 + ln15] = (bf16_t)o;
          }
        }
      }
    }
  } else {
    f32x4 acc[16];
    #pragma unroll
    for (int f = 0; f < 16; ++f) acc[f] = (f32x4){0.f, 0.f, 0.f, 0.f};
    gemm_core_128x128(xn, 2048, m0, wfT, 2048, 1024, 2048, As, B0s, acc);
    const bool is_k = (wn == 0);
    #pragma unroll
    for (int i = 0; i < 4; ++i) {
      #pragma unroll
      for (int rr = 0; rr < 4; ++rr) {
        const int row = rb + i * 16 + rr;
        const int b = row >> 11, n = row & 2047;
        float vals[4];
        #pragma unroll
        for (int j = 0; j < 4; ++j) vals[j] = acc[i * 4 + j][rr];
        if (is_k) {
          const float fn = (float)n;
          float s0, c0, s1, c1;
          __sincosf(fn * invf0, &s0, &c0);
          __sincosf(fn * invf1, &s1, &c1);
          #pragma unroll
          for (int j = 0; j < 4; ++j) {
            const float rot = (j < 2) ? -vals[j + 2] : vals[j - 2];
            const float c = (j & 1) ? c1 : c0;
            const float s = (j & 1) ? s1 : s0;
            K[((size_t)b * 2048 + n) * 64 + j * 16 + ln15] = (bf16_t)(vals[j] * c + rot * s);
          }
        } else {
          #pragma unroll
          for (int j = 0; j < 4; ++j)
            Vt[((size_t)b * 64 + j * 16 + ln15) * 2048 + n] = (bf16_t)vals[j];
        }
      }
    }
  }
}

// ===========================================================================
// Register-prefetch pipelined cores (R5 schedule, R6 waitcnt intrinsics)
// ===========================================================================

#define FF_STG() {                                                           \
    char* lA_ = lds + sst + w * 1024;                                        \
    gload_lds16(gA, lA_);                                                    \
    gload_lds16(gA + (size_t)128 * 2048, lA_ + 8192);                        \
    char* lB_ = lds + 65536 + sst + w * 1024;                                \
    gload_lds16(gB0, lB_);                                                   \
    gload_lds16(gB1, lB_ + 8192);                                            \
    gA += 32; gB0 += 32; gB1 += 32;                                          \
    sst = (sst + 16384) & 65535; }

#define FF_RD(DA, DB) {                                                      \
    _Pragma("unroll")                                                        \
    for (int mf_ = 0; mf_ < 8; ++mf_)                                        \
      DA[mf_] = *(const bf16x8*)(lds + srd + wm * 8192 + mf_ * 1024 + ro);   \
    _Pragma("unroll")                                                        \
    for (int nf_ = 0; nf_ < 4; ++nf_)                                        \
      DB[nf_] = *(const bf16x8*)(lds + 65536 + srd + wn * 4096 + nf_ * 1024 + ro); \
    srd = (srd + 16384) & 65535;                                             \
    __builtin_amdgcn_sched_barrier(0); }

#define FF_MM(SA, SB) {                                                      \
    __builtin_amdgcn_s_setprio(1);                                           \
    _Pragma("unroll")                                                        \
    for (int mf_ = 0; mf_ < 8; ++mf_) {                                      \
      _Pragma("unroll")                                                      \
      for (int nf_ = 0; nf_ < 4; ++nf_)                                      \
        acc[mf_][nf_] = mfma16(SA[mf_], SB[nf_], acc[mf_][nf_]);             \
    }                                                                        \
    __builtin_amdgcn_s_setprio(0); }

#define FF_SYNC4() { WAITCNT_VM(4); __builtin_amdgcn_s_barrier(); }

// ---------------------------------------------------------------------------
// GEMM1b (ff): BM=256, B = 128 gate + 128 x rows interleaved (16-row), BK=32,
// 512 thr (8 waves 2Mx4N). 4-slot LDS ring (128 KB), reg-prefetch pipeline.
// ---------------------------------------------------------------------------
__global__ __launch_bounds__(512, 2) void gemm1_ff_kernel(
    const bf16_t* __restrict__ xn, const bf16_t* __restrict__ wfT,
    bf16_t* __restrict__ A2)
{
  __shared__ __align__(16) char lds[131072];
  const int m0 = blockIdx.x * 256;
  const int c0 = blockIdx.y * 128;
  const int t = threadIdx.x;
  const int w = t >> 6, lane = t & 63;
  const int quad = lane >> 4, ln15 = lane & 15;
  const int wm = w & 1, wn = w >> 1;          // 2 x 4 wave grid

  const int p  = w * 64 + lane;
  const int r  = p >> 2;
  const int cl = (p & 3) ^ ((r >> 1) & 3);
  const bf16_t* gA = xn + (size_t)(m0 + r) * 2048 + cl * 8;
  const int r2 = r + 128;
  const int cm0 = c0 + ((r  >> 5) << 4) + (r  & 15);
  const int cm1 = c0 + ((r2 >> 5) << 4) + (r2 & 15);
  const int wr0 = ((r  >> 4) & 1) ? (1152 + cm0) : (9344 + cm0);
  const int wr1 = ((r2 >> 4) & 1) ? (1152 + cm1) : (9344 + cm1);
  const bf16_t* gB0 = wfT + (size_t)wr0 * 2048 + cl * 8;
  const bf16_t* gB1 = wfT + (size_t)wr1 * 2048 + cl * 8;

  const int ro = ln15 * 64 + ((quad ^ ((ln15 >> 1) & 3)) * 16);

  f32x4 acc[8][4];
  #pragma unroll
  for (int mf = 0; mf < 8; ++mf)
    #pragma unroll
    for (int nf = 0; nf < 4; ++nf)
      acc[mf][nf] = (f32x4){0.f, 0.f, 0.f, 0.f};

  int sst = 0, srd = 0;
  // prologue: stage tiles 0,1,2 (12 loads)
  #pragma unroll
  for (int pt = 0; pt < 3; ++pt) FF_STG();
  // tiles 0,1 complete (oldest 8 of 12 retired); tile 2 still in flight
  FF_SYNC4();

  bf16x8 fA[8], fB[4], nA[8], nB[4];
  FF_RD(fA, fB);                         // frags(0); srd -> 16384

  // main loop: tt = 0..60 (uniform). invariant at top: only tile tt+2 in flight
  for (int i = 0; i < 30; ++i) {
    FF_STG(); FF_RD(nA, nB); FF_MM(fA, fB); FF_SYNC4();   // tt even
    FF_STG(); FF_RD(fA, fB); FF_MM(nA, nB); FF_SYNC4();   // tt odd
  }
  FF_STG(); FF_RD(nA, nB); FF_MM(fA, fB); FF_SYNC4();     // tt=60 (stages 63)
  // tail: tiles 61..63
  FF_RD(fA, fB); FF_MM(nA, nB);                           // tt=61, reads 62
  WAITCNT_VM(0);
  __builtin_amdgcn_s_barrier();
  FF_RD(nA, nB); FF_MM(fA, fB);                           // tt=62, reads 63
  FF_MM(nA, nB);                                          // tt=63

  // epilogue: silu(gate)*x -> A2 cols [0,8192)
  const int row0 = m0 + wm * 128 + quad * 4;
  const int col0 = c0 + wn * 32 + ln15;
  #pragma unroll
  for (int mf = 0; mf < 8; ++mf)
    #pragma unroll
    for (int rr = 0; rr < 4; ++rr) {
      bf16_t* dst = A2 + (size_t)(row0 + mf * 16 + rr) * 9216 + col0;
      #pragma unroll
      for (int j = 0; j < 2; ++j) {
        const float g  = acc[mf][2 * j][rr];
        const float xv = acc[mf][2 * j + 1][rr];
        dst[j * 16] = (bf16_t)(xv * (g / (1.f + exp2f(-g * LOG2E))));
      }
    }
}

#define G2_STG() {                                                           \
    char* lA_ = lds + sstA + w * 1024;                                       \
    gload_lds16(gA, lA_);                                                    \
    gload_lds16(gA + (size_t)128 * 9216, lA_ + 8192);                        \
    gload_lds16(gB, lds + 65536 + sstB + w * 1024);                          \
    gA += 32; gB += 32;                                                      \
    sstA = (sstA + 16384) & 65535;                                           \
    sstB = (sstB + 8192) & 32767; }

#define G2_RD(DA, DB) {                                                      \
    _Pragma("unroll")                                                        \
    for (int mf_ = 0; mf_ < 4; ++mf_)                                        \
      DA[mf_] = *(const bf16x8*)(lds + srdA + wm * 4096 + mf_ * 1024 + ro);  \
    _Pragma("unroll")                                                        \
    for (int nf_ = 0; nf_ < 4; ++nf_)                                        \
      DB[nf_] = *(const bf16x8*)(lds + 65536 + srdB + wn * 4096 + nf_ * 1024 + ro); \
    srdA = (srdA + 16384) & 65535;                                           \
    srdB = (srdB + 8192) & 32767;                                            \
    __builtin_amdgcn_sched_barrier(0); }

#define G2_MM(SA, SB) {                                                      \
    __builtin_amdgcn_s_setprio(1);                                           \
    _Pragma("unroll")                                                        \
    for (int mf_ = 0; mf_ < 4; ++mf_) {                                      \
      _Pragma("unroll")                                                      \
      for (int nf_ = 0; nf_ < 4; ++nf_)                                      \
        acc[mf_][nf_] = mfma16(SA[mf_], SB[nf_], acc[mf_][nf_]);             \
    }                                                                        \
    __builtin_amdgcn_s_setprio(0); }

#define G2_SYNC3() { WAITCNT_VM(3); __builtin_amdgcn_s_barrier(); }

// ---------------------------------------------------------------------------
// GEMM2: out = A2(4096x9216) @ w2T^T. BM=256/BN=128, BK=32, 512 thr (4Mx2N).
// Grid 16x16=256 blocks, no split-K, direct f32 stores. 4-slot ring (96 KB),
// reg-prefetch pipeline.
// ---------------------------------------------------------------------------
__global__ __launch_bounds__(512, 2) void gemm2_kernel(
    const bf16_t* __restrict__ A2, const bf16_t* __restrict__ w2T,
    float* __restrict__ out)
{
  __shared__ __align__(16) char lds[98304];
  const int m0 = blockIdx.x * 256;
  const int n0 = blockIdx.y * 128;
  const int t = threadIdx.x;
  const int w = t >> 6, lane = t & 63;
  const int quad = lane >> 4, ln15 = lane & 15;
  const int wm = w & 3, wn = w >> 2;          // 4 x 2 wave grid

  const int p  = w * 64 + lane;
  const int r  = p >> 2;
  const int cl = (p & 3) ^ ((r >> 1) & 3);
  const bf16_t* gA = A2  + (size_t)(m0 + r) * 9216 + cl * 8;
  const bf16_t* gB = w2T + (size_t)(n0 + r) * 9216 + cl * 8;

  const int ro = ln15 * 64 + ((quad ^ ((ln15 >> 1) & 3)) * 16);

  f32x4 acc[4][4];
  #pragma unroll
  for (int mf = 0; mf < 4; ++mf)
    #pragma unroll
    for (int nf = 0; nf < 4; ++nf)
      acc[mf][nf] = (f32x4){0.f, 0.f, 0.f, 0.f};

  int sstA = 0, sstB = 0, srdA = 0, srdB = 0;
  #pragma unroll
  for (int pt = 0; pt < 3; ++pt) G2_STG();
  // 9 loads out; wait -> 3 remain: tiles 0,1 complete
  G2_SYNC3();

  bf16x8 fA[4], fB[4], nA[4], nB[4];
  G2_RD(fA, fB);                          // frags(0)

  // main loop: tt = 0..284 (uniform)
  for (int i = 0; i < 142; ++i) {
    G2_STG(); G2_RD(nA, nB); G2_MM(fA, fB); G2_SYNC3();
    G2_STG(); G2_RD(fA, fB); G2_MM(nA, nB); G2_SYNC3();
  }
  G2_STG(); G2_RD(nA, nB); G2_MM(fA, fB); G2_SYNC3();     // tt=284 (stages 287)
  // tail: 285..287
  G2_RD(fA, fB); G2_MM(nA, nB);                           // tt=285, reads 286
  WAITCNT_VM(0);
  __builtin_amdgcn_s_barrier();
  G2_RD(nA, nB); G2_MM(fA, fB);                           // tt=286, reads 287
  G2_MM(nA, nB);                                          // tt=287

  const int row0 = m0 + wm * 64 + quad * 4;
  const int col0 = n0 + wn * 64 + ln15;
  #pragma unroll
  for (int mf = 0; mf < 4; ++mf)
    #pragma unroll
    for (int rr = 0; rr < 4; ++rr) {
      float* dst = out + (size_t)(row0 + mf * 16 + rr) * 2048 + col0;
      #pragma unroll
      for (int nf = 0; nf < 4; ++nf)
        dst[nf * 16] = acc[mf][nf][rr];
    }
}

// ---------------------------------------------------------------------------
// Causal MQA flash attention -> A2[:, 8192 + h*64 + d]. Paired Q-tiles
// (qt = p and 31-p), grid (16,32), 512 blocks, LDS 32 KB.
// R15: setprio around MFMA clusters. R16: Q-hoist — Q fragments read into
// registers once per half (after vm(0)+barrier for cross-wave visibility)
// instead of per-K-tile LDS reads on the post-barrier critical path.
// ---------------------------------------------------------------------------
__global__ __launch_bounds__(256, 2) void attn_kernel(
    const bf16_t* __restrict__ Q, const bf16_t* __restrict__ Kg_,
    const bf16_t* __restrict__ Vt, bf16_t* __restrict__ A2)
{
  __shared__ __align__(16) bf16_t Qs[64 * 64];
  __shared__ __align__(16) bf16_t Ks[64 * 64];
  __shared__ __align__(16) bf16_t Vs[64 * 64];
  __shared__ __align__(16) bf16_t Ps[64 * 64];
  const int pidx = blockIdx.x, bh = blockIdx.y;
  const int b = bh >> 4, h = bh & 15;
  const int t = threadIdx.x;
  const int wave = t >> 6, lane = t & 63;
  const int quad = lane >> 4, ln15 = lane & 15;

  const bf16_t* Kg = Kg_ + (size_t)b * 2048 * 64;
  const bf16_t* Vg = Vt + (size_t)b * 64 * 2048;

  for (int hlf = 0; hlf < 2; ++hlf) {
    const int qt = hlf ? (31 - pidx) : pidx;
    const int qm0 = qt * 64;
    const bf16_t* Qg = Q + ((size_t)bh * 2048 + qm0) * 64;

    { // stage Q tile (8 KB, 2 rounds)
      const bf16_t* g = Qg + (size_t)(t >> 3) * 64 + ((t & 7) << 3);
      char* l = (char*)Qs + wave * 1024;
      gload_lds16(g,           l);
      gload_lds16(g + 32 * 64, l + 4096);
    }
    // Q-hoist: drain Q staging (cross-wave) and pull the jt-invariant
    // Q fragments into registers once.
    WAITCNT_VM(0);
    __builtin_amdgcn_s_barrier();
    const bf16x8 aq0 = *(const bf16x8*)(Qs + (wave * 16 + ln15) * 64 + 0 * 32 + quad * 8);
    const bf16x8 aq1 = *(const bf16x8*)(Qs + (wave * 16 + ln15) * 64 + 1 * 32 + quad * 8);

    float mstate[4], lstate[4];
    f32x4 o_acc[4];
    #pragma unroll
    for (int rr = 0; rr < 4; ++rr) { mstate[rr] = -1e30f; lstate[rr] = 0.f; }
    #pragma unroll
    for (int jd = 0; jd < 4; ++jd) o_acc[jd] = (f32x4){0.f, 0.f, 0.f, 0.f};

    const int njt = qt + 1;
    for (int jt = 0; jt < njt; ++jt) {
      { // stage K, V tiles (8 KB each)
        const bf16_t* kg = Kg + (size_t)(jt * 64 + (t >> 3)) * 64 + ((t & 7) << 3);
        char* lk = (char*)Ks + wave * 1024;
        gload_lds16(kg,           lk);
        gload_lds16(kg + 32 * 64, lk + 4096);
        const bf16_t* vg = Vg + (size_t)(t >> 3) * 2048 + jt * 64 + ((t & 7) << 3);
        char* lv = (char*)Vs + wave * 1024;
        gload_lds16(vg,                   lv);
        gload_lds16(vg + (size_t)32*2048, lv + 4096);
      }
      __syncthreads();

      f32x4 sA[4];
      #pragma unroll
      for (int j = 0; j < 4; ++j) sA[j] = (f32x4){0.f, 0.f, 0.f, 0.f};
      __builtin_amdgcn_s_setprio(1);
      #pragma unroll
      for (int j = 0; j < 4; ++j) {
        bf16x8 bk0 = *(const bf16x8*)(Ks + (j * 16 + ln15) * 64 + 0 * 32 + quad * 8);
        sA[j] = mfma16(aq0, bk0, sA[j]);
      }
      #pragma unroll
      for (int j = 0; j < 4; ++j) {
        bf16x8 bk1 = *(const bf16x8*)(Ks + (j * 16 + ln15) * 64 + 1 * 32 + quad * 8);
        sA[j] = mfma16(aq1, bk1, sA[j]);
      }
      __builtin_amdgcn_s_setprio(0);

      const bool needmask = (jt * 64 + 63 > qm0 + wave * 16);
      const int row0 = qm0 + wave * 16 + quad * 4;
      float alpha[4];
      #pragma unroll
      for (int rr = 0; rr < 4; ++rr) {
        const int rowg = row0 + rr;
        if (needmask) {
          #pragma unroll
          for (int j = 0; j < 4; ++j) {
            const int colg = jt * 64 + j * 16 + ln15;
            if (colg > rowg) sA[j][rr] = -1e30f;
          }
        }
        float mx = fmaxf(fmaxf(sA[0][rr], sA[1][rr]),
                         fmaxf(sA[2][rr], sA[3][rr]));
        mx = fmaxf(mx, __shfl_xor(mx, 1));
        mx = fmaxf(mx, __shfl_xor(mx, 2));
        mx = fmaxf(mx, __shfl_xor(mx, 4));
        mx = fmaxf(mx, __shfl_xor(mx, 8));
        const float mold = mstate[rr];
        const float mnew = fmaxf(mold, mx);
        const float al = exp2f((mold - mnew) * LOG2E);
        float rsum = 0.f;
        #pragma unroll
        for (int j = 0; j < 4; ++j) {
          const float p = exp2f((sA[j][rr] - mnew) * LOG2E);
          sA[j][rr] = p;
          rsum += p;
        }
        rsum += __shfl_xor(rsum, 1);
        rsum += __shfl_xor(rsum, 2);
        rsum += __shfl_xor(rsum, 4);
        rsum += __shfl_xor(rsum, 8);
        lstate[rr] = lstate[rr] * al + rsum;
        mstate[rr] = mnew;
        alpha[rr] = al;
      }
      #pragma unroll
      for (int jd = 0; jd < 4; ++jd)
        #pragma unroll
        for (int rr = 0; rr < 4; ++rr)
          o_acc[jd][rr] *= alpha[rr];
      #pragma unroll
      for (int j = 0; j < 4; ++j)
        #pragma unroll
        for (int rr = 0; rr < 4; ++rr)
          Ps[wave * 1024 + (quad * 4 + rr) * 64 + j * 16 + ln15] = (bf16_t)sA[j][rr];

      __builtin_amdgcn_s_setprio(1);
      #pragma unroll
      for (int ks = 0; ks < 2; ++ks) {
        bf16x8 ap = *(const bf16x8*)(Ps + wave * 1024 + ln15 * 64 + ks * 32 + quad * 8);
        #pragma unroll
        for (int jd = 0; jd < 4; ++jd) {
          bf16x8 bv = *(const bf16x8*)(Vs + (jd * 16 + ln15) * 64 + ks * 32 + quad * 8);
          o_acc[jd] = mfma16(ap, bv, o_acc[jd]);
        }
      }
      __builtin_amdgcn_s_setprio(0);
      __syncthreads();
    }

    const int row0 = qm0 + wave * 16 + quad * 4;
    #pragma unroll
    for (int rr = 0; rr < 4; ++rr) {
      const float inv = 1.f / lstate[rr];
      bf16_t* dst = A2 + ((size_t)b * 2048 + row0 + rr) * 9216 + 8192 + h * 64 + ln15;
      #pragma unroll
      for (int jd = 0; jd < 4; ++jd)
        dst[jd * 16] = (bf16_t)(o_acc[jd][rr] * inv);
    }
  }
}

// ---------------------------------------------------------------------------
extern "C" void kernel_launch(void* const* d_in, const int* in_sizes, int n_in,
                              void* d_out, int out_size, void* d_ws, size_t ws_size,
                              hipStream_t stream)
{
  const float* x      = (const float*)d_in[0];
  const float* gamma  = (const float*)d_in[1];
  const float* wfused = (const float*)d_in[2];
  const float* watt   = (const float*)d_in[3];
  const float* wff    = (const float*)d_in[4];
  const float* qa     = (const float*)d_in[5];
  const float* qb     = (const float*)d_in[6];
  const float* ka     = (const float*)d_in[7];
  const float* kb     = (const float*)d_in[8];
  const float* va     = (const float*)d_in[9];
  const float* vb     = (const float*)d_in[10];
  const float* oa     = (const float*)d_in[11];
  const float* ob     = (const float*)d_in[12];
  float* out = (float*)d_out;

  char* ws = (char*)d_ws;
  bf16_t* xn  = (bf16_t*)(ws);                    // 16,777,216
  bf16_t* wfT = (bf16_t*)(ws + 16777216);         // 71,827,456
  bf16_t* w2T = (bf16_t*)(ws + 88604672);         // 37,748,736
  bf16_t* A2  = (bf16_t*)(ws + 126353408);        // 75,497,472
  bf16_t* Qr  = (bf16_t*)(ws + 201850880);        //  8,388,608
  bf16_t* Kr  = (bf16_t*)(ws + 210239488);        //    524,288
  bf16_t* Vtr = (bf16_t*)(ws + 210763776);        //    524,288

  ln_kernel<<<dim3(4096), dim3(256), 0, stream>>>(x, gamma, xn);
  transpose_wf_kernel<<<dim3(274, 32), dim3(256), 0, stream>>>(
      wfused, qa, qb, ka, kb, va, vb, wfT);
  transpose_w2_kernel<<<dim3(32, 144), dim3(256), 0, stream>>>(
      wff, watt, oa, ob, w2T);
  gemm1_qkv_kernel<<<dim3(32, 5), dim3(256), 0, stream>>>(xn, wfT, Qr, Kr, Vtr);
  gemm1_ff_kernel<<<dim3(16, 64), dim3(512), 0, stream>>>(xn, wfT, A2);
  attn_kernel<<<dim3(16, 32), dim3(256), 0, stream>>>(Qr, Kr, Vtr, A2);
  gemm2_kernel<<<dim3(16, 16), dim3(512), 0, stream>>>(A2, w2T, out);
}